// Round 8
// baseline (257.789 us; speedup 1.0000x reference)
//
#include <hip/hip_runtime.h>
#include <math.h>

#define NGRID 9801
#define NB 11            // blocks per dim (both scales)
#define NBLK (NB*NB)     // 121
#define BATCH 16
#define NFEAT 36

// ---------------- tables ----------------
__global__ void init_tables(float* __restrict__ rgam, float* __restrict__ convt,
                            float* __restrict__ meanf, float* __restrict__ w1d) {
    int i = blockIdx.x * blockDim.x + threadIdx.x;
    if (i < NGRID) {
        double a = (double)(float)(0.2 + 0.001 * (double)i);  // match float32 grid
        double g1 = lgamma(1.0 / a);
        double g2 = lgamma(2.0 / a);
        double g3 = lgamma(3.0 / a);
        rgam[i]  = (float)exp(2.0 * g2 - g1 - g3);
        convt[i] = (float)sqrt(exp(g1 - g3));
        meanf[i] = (float)exp(g2 - g1);
    }
    if (i == 0) {
        double g[7], s = 0.0;
        for (int k = 0; k < 7; ++k) { double d = (double)(k - 3); g[k] = exp(-d * d * 18.0 / 49.0); s += g[k]; }
        for (int k = 0; k < 7; ++k) w1d[k] = (float)(g[k] / s);
    }
}

__device__ __forceinline__ float bperm(int addr, float v) {
    return __int_as_float(__builtin_amdgcn_ds_bpermute(addr, __float_as_int(v)));
}

// ---------------- fused MSCN + in-register per-block stats (pipelined) --------
// One WG per (NIQE block, batch).
//   K=96: 2 slabs(48 cols) x 4 strips(24 rows) = 8 waves (512 thr).
//   K=48: 1 slab x 4 strips(12 rows) = 4 waves (256 thr).
// Sliding-window separable 7x7 conv; norm in registers only. 25 AGGD sums
// accumulate during the walk; cross-wave circular-wrap products contribute 0
// in the walk and are patched from small LDS seam buffers afterwards.
// Row addressing is wave-uniform (SALU); 8 bperms/row (6 hconv + 2 products).
template <int K, bool WDS>
__global__ __launch_bounds__(K == 96 ? 512 : 256) void fused_mscn_stats(
        const float* __restrict__ img, float* __restrict__ dsout,
        const float* __restrict__ w1d, float* __restrict__ stats) {
    constexpr int NSLAB = K / 48;
    constexpr int NSTRIP = 4;
    constexpr int WAVES = NSLAB * NSTRIP;
    constexpr int SROWS = K / NSTRIP;
    constexpr int W = K * NB;
    constexpr int H = W;

    __shared__ float lastrow[NSTRIP][K];            // each strip's last norm row
    __shared__ float edgeL[NSTRIP][NSLAB][SROWS];   // per-row slab-edge norm (K=96)
    __shared__ float edgeR[NSTRIP][NSLAB][SROWS];
    __shared__ float redf[WAVES][15];
    __shared__ float redc[WAVES][10];

    const int tid = threadIdx.x;
    const int lane = tid & 63;
    const int wv = tid >> 6;
    const int slab = wv % NSLAB;
    const int strip = wv / NSLAB;
    const int bIdx = blockIdx.x;
    const int b = blockIdx.y;
    const int bh = bIdx / NB, bw = bIdx % NB;
    const int x0 = bw * K + slab * 48;
    const int gx = x0 - 3 + lane;
    const int gxc = min(max(gx, 0), W - 1);
    const int r0 = bh * K + strip * SROWS;
    const int basem3 = (lane - 3) << 2;
    const bool act = (lane >= 3) && (lane <= 50);
    int am1, ap1;
    if constexpr (NSLAB == 1) {
        am1 = ((lane == 3) ? 50 : (lane - 1)) << 2;
        ap1 = ((lane == 50) ? 3 : (lane + 1)) << 2;
    } else {
        am1 = ((lane - 1) & 63) << 2;   // lane3 reads zeroed lane2 -> fixup later
        ap1 = ((lane + 1) & 63) << 2;   // lane50 reads zeroed lane51 -> fixup later
    }

    const float* imb = img + (size_t)b * H * W;     // uniform base
    const float w0=w1d[0], w1=w1d[1], w2=w1d[2], w3=w1d[3], w4=w1d[4], w5=w1d[5], w6=w1d[6];

    // wave-uniform row cursor -> SALU; per-lane part is gxc only
    int row = r0 - 3;
    int roff = min(max(row, 0), H - 1) * W;
    auto ld = [&]() -> float {
        float v = imb[(size_t)(roff + gxc)];
        ++row;
        roff = min(max(row, 0), H - 1) * W;   // uniform
        return v;
    };

    float pa0, pa1, pa2, pa4, pa5, pa6, vHp;
    auto issue_raw = [&](float v) {
        pa0 = bperm(basem3,      v);
        pa1 = bperm(basem3 + 4,  v);
        pa2 = bperm(basem3 + 8,  v);
        pa4 = bperm(basem3 + 16, v);
        pa5 = bperm(basem3 + 20, v);
        pa6 = bperm(basem3 + 24, v);
        vHp = v;
    };
    auto combine_raw = [&](float& om, float& oq) {
        om = ((w0*pa0 + w1*pa1) + (w2*pa2 + w3*vHp)) + ((w4*pa4 + w5*pa5) + w6*pa6);
        oq = ((w0*pa0*pa0 + w1*pa1*pa1) + (w2*pa2*pa2 + w3*vHp*vHp))
           + ((w4*pa4*pa4 + w5*pa5*pa5) + w6*pa6*pa6);
    };

    float acc[5][3];
    #pragma unroll
    for (int s = 0; s < 5; ++s) { acc[s][0] = acc[s][1] = acc[s][2] = 0.f; }
    int cl[5] = {0,0,0,0,0}, cr[5] = {0,0,0,0,0};

    auto upd = [&](int s, float v) {
        float vp = fmaxf(v, 0.f);
        acc[s][0] = fmaf(vp, vp, acc[s][0]);   // sr2
        acc[s][1] = fmaf(v, v, acc[s][1]);     // ssq (sl2 = ssq - sr2 later)
        acc[s][2] += fabsf(v);                 // sum |v|
        cl[s] += __popcll(__ballot(v < 0.f));  // scalar-unit counts
        cr[s] += __popcll(__ballot(v > 0.f));
    };

    // prologue: fill 7-row hconv ring (rows r0-3 .. r0+3) + pend row r0+4
    float mr0,mr1,mr2,mr3,mr4,mr5,mr6, qr0,qr1,qr2,qr3,qr4,qr5,qr6;
    float rA, rB, rC, rD;
    float vN = ld();
    { float v=vN; vN=ld(); issue_raw(v); combine_raw(mr0,qr0); }
    { float v=vN; vN=ld(); issue_raw(v); combine_raw(mr1,qr1); }
    { float v=vN; vN=ld(); issue_raw(v); combine_raw(mr2,qr2); }
    { float v=vN; vN=ld(); issue_raw(v); combine_raw(mr3,qr3); rA=v; }
    { float v=vN; vN=ld(); issue_raw(v); combine_raw(mr4,qr4); rB=v; }
    { float v=vN; vN=ld(); issue_raw(v); combine_raw(mr5,qr5); rC=v; }
    { float v=vN; vN=ld(); issue_raw(v); combine_raw(mr6,qr6); rD=v; }
    { float v=vN; vN=ld(); issue_raw(v); }   // pends = row r0+4

    // product-shift state: SLa=SL(y-1), SLb=SL(y-2), SRa=SR(y-1), SRb=SR(y-2)
    float SLa = 0.f, SLb = 0.f, SRa = 0.f, SRb = 0.f;
    float normP = 0.f, normP2 = 0.f;
    float firstN = 0.f, dsSave = 0.f;
    const bool dsw = WDS && (lane & 1) && (lane >= 3) && (lane <= 49);

    #pragma unroll 6
    for (int yy = 0; yy < SROWS; ++yy) {
        const int y = r0 + yy;
        // 1) stats for row y-1 (pure VALU; bperms issued >=1 iter earlier)
        if (yy > 0) {
            upd(0, normP);
            upd(1, normP * SLa);
            upd(2, normP * normP2);
            upd(3, normP * SLb);
            upd(4, normP * SRb);
        }
        // 2) vertical combine for row y (ring ready since last iter)
        float mu = ((w0*mr0 + w1*mr1) + (w2*mr2 + w3*mr3)) + ((w4*mr4 + w5*mr5) + w6*mr6);
        float s2 = ((w0*qr0 + w1*qr1) + (w2*qr2 + w3*qr3)) + ((w4*qr4 + w5*qr5) + w6*qr6);
        float sig = __builtin_amdgcn_sqrtf(fabsf(s2 - mu * mu));
        float nrm = (rA - mu) * __builtin_amdgcn_rcpf(sig + 1.0f);
        float cur = act ? nrm : 0.f;

        // 3) captures
        if (yy == 0) firstN = cur;
        if constexpr (NSLAB == 2) {
            if (lane == 3)  edgeL[strip][slab][yy] = cur;
            if (lane == 50) edgeR[strip][slab][yy] = cur;
        }
        if (yy == SROWS - 1 && act) lastrow[strip][slab * 48 + lane - 3] = cur;

        // 4) fused 2x2-mean downsample of raw input
        if constexpr (WDS) {
            float hs = rA + __shfl_down(rA, 1);
            if ((y & 1) == 0) dsSave = hs;
            else if (dsw)
                dsout[((size_t)b * (H / 2) + (y >> 1)) * (W / 2) + (gx >> 1)] = 0.25f * (dsSave + hs);
        }

        // 5) rotate product state; issue this row's product bperms
        SLb = SLa; SRb = SRa;
        SLa = bperm(am1, cur);
        SRa = bperm(ap1, cur);
        normP2 = normP; normP = cur;

        // 6) hconv combine for row y+4 (pends issued last iter) + ring shift
        float mh, qh; combine_raw(mh, qh);
        mr0=mr1; mr1=mr2; mr2=mr3; mr3=mr4; mr4=mr5; mr5=mr6; mr6=mh;
        qr0=qr1; qr1=qr2; qr2=qr3; qr3=qr4; qr4=qr5; qr5=qr6; qr6=qh;

        // 7) raw ring shift, issue next raw bperms, prefetch next load
        rA=rB; rB=rC; rC=rD; rD=vHp;
        float vv = vN; vN = ld();
        issue_raw(vv);
    }
    // epilogue: stats for the strip's last row
    upd(0, normP);
    upd(1, normP * SLa);
    upd(2, normP * normP2);
    upd(3, normP * SLb);
    upd(4, normP * SRb);

    __syncthreads();

    // ---- row-seam fixup: products of row r0 with block-circular previous row ----
    {
        const int ps = (strip + NSTRIP - 1) % NSTRIP;
        int j  = slab * 48 + (lane - 3);
        int js = act ? j : 0;
        int jm1 = (js + K - 1) % K;
        int jp1 = (js + 1) % K;
        float pv  = act ? lastrow[ps][js]  : 0.f;
        float pvL = act ? lastrow[ps][jm1] : 0.f;
        float pvR = act ? lastrow[ps][jp1] : 0.f;
        upd(2, firstN * pv);
        upd(3, firstN * pvL);
        upd(4, firstN * pvR);
    }

    // ---- column-seam fixup (K=96 only): slab-edge wrap products ----
    if constexpr (NSLAB == 2) {
        if (lane < SROWS) {
            int r = lane;
            if (slab == 0) {
                float c0  = edgeL[strip][0][r];   // n[r][0]
                float e95 = edgeR[strip][1][r];   // n[r][95]
                upd(1, c0 * e95);
                if (r > 0) {
                    upd(3, c0 * edgeR[strip][1][r - 1]);
                    upd(4, edgeR[strip][0][r] * edgeL[strip][1][r - 1]);  // col47 * n[r-1][48]
                }
            } else {
                float c48 = edgeL[strip][1][r];   // n[r][48]
                float e47 = edgeR[strip][0][r];   // n[r][47]
                upd(1, c48 * e47);
                if (r > 0) {
                    upd(3, c48 * edgeR[strip][0][r - 1]);
                    upd(4, edgeR[strip][1][r] * edgeL[strip][0][r - 1]); // col95 * n[r-1][0]
                }
            }
        }
    }

    // ---- reduce: 15 floats via shuffles; counts are wave-uniform scalars ----
    #pragma unroll
    for (int off = 32; off >= 1; off >>= 1)
        #pragma unroll
        for (int s = 0; s < 5; ++s) {
            acc[s][0] += __shfl_down(acc[s][0], off);
            acc[s][1] += __shfl_down(acc[s][1], off);
            acc[s][2] += __shfl_down(acc[s][2], off);
        }
    if (lane == 0) {
        #pragma unroll
        for (int s = 0; s < 5; ++s) {
            redf[wv][s*3+0] = acc[s][0];
            redf[wv][s*3+1] = acc[s][1];
            redf[wv][s*3+2] = acc[s][2];
            redc[wv][s*2+0] = (float)cl[s];
            redc[wv][s*2+1] = (float)cr[s];
        }
    }
    __syncthreads();
    if (tid < 15) {
        float s = 0.f;
        #pragma unroll
        for (int w = 0; w < WAVES; ++w) s += redf[w][tid];
        stats[((size_t)b * NBLK + bIdx) * 25 + tid] = s;
    } else if (tid < 25) {
        int t = tid - 15;
        float s = 0.f;
        #pragma unroll
        for (int w = 0; w < WAVES; ++w) s += redc[w][t];
        stats[((size_t)b * NBLK + bIdx) * 25 + tid] = s;
    }
}

// ---------------- AGGD closed-form + binary-search argmin ----------------
__global__ __launch_bounds__(256) void aggd_kernel(
        const float* __restrict__ stats1, const float* __restrict__ stats2,
        const float* __restrict__ rgam, const float* __restrict__ convt,
        const float* __restrict__ meanf, float* __restrict__ feats) {
    __shared__ float rg[NGRID];
    for (int i = threadIdx.x; i < NGRID; i += 256) rg[i] = rgam[i];
    __syncthreads();

    int gid = blockIdx.x * 256 + threadIdx.x;
    if (gid >= 2 * BATCH * NBLK * 5) return;
    int s = gid % 5; int t = gid / 5;
    int blk = t % NBLK; t /= NBLK;
    int b = t % BATCH; int scale = t / BATCH;

    const float* st = (scale ? stats2 : stats1) + ((size_t)b * NBLK + blk) * 25;
    float sr2 = st[s*3+0], ssq = st[s*3+1], sab = st[s*3+2];
    float cl = st[15 + 2*s], cr = st[15 + 2*s + 1];
    float sl2 = fmaxf(ssq - sr2, 0.f);
    float n = scale ? (48.f * 48.f) : (96.f * 96.f);

    float lstd = sqrtf(sl2 / (cl + 1e-8f));
    float rstd = sqrtf(sr2 / (cr + 1e-8f));
    float gh = lstd / rstd;
    float mab = sab / n;
    float msq = ssq / n;
    float rhat = mab * mab / msq;
    float g2 = gh * gh;
    float x = rhat * (gh * g2 + 1.f) * (gh + 1.f) / ((g2 + 1.f) * (g2 + 1.f));

    int lo = 0, hi = NGRID;
    while (lo < hi) {
        int mid = (lo + hi) >> 1;
        if (rg[mid] < x) lo = mid + 1; else hi = mid;
    }
    int gi;
    if (lo <= 0) gi = 0;
    else if (lo >= NGRID) gi = NGRID - 1;
    else {
        float dlo = x - rg[lo - 1];
        float dhi = rg[lo] - x;
        gi = (dlo <= dhi) ? lo - 1 : lo;   // tie -> lower index (first-min)
    }

    float alpha = (float)(0.2 + 0.001 * (double)gi);
    float cv = convt[gi];
    float lb = lstd * cv, rb = rstd * cv;
    float* fo = feats + ((size_t)b * NBLK + blk) * NFEAT + (scale ? 18 : 0);
    if (s == 0) {
        fo[0] = alpha;
        fo[1] = 0.5f * (lb + rb);
    } else {
        int o = 2 + (s - 1) * 4;
        fo[o]     = alpha;
        fo[o + 1] = (rb - lb) * meanf[gi];
        fo[o + 2] = lb;
        fo[o + 3] = rb;
    }
}

// ---------------- per-batch covariance + solve + score ----------------
__global__ __launch_bounds__(256) void score_kernel(
        const float* __restrict__ feats, const float* __restrict__ mu_pris,
        const float* __restrict__ cov_pris, float* __restrict__ out) {
    __shared__ float F[NBLK][NFEAT];
    __shared__ double mu[NFEAT];
    __shared__ double A[NFEAT][NFEAT + 1];
    __shared__ double dff[NFEAT];
    __shared__ double xs[NFEAT];
    int b = blockIdx.x, tid = threadIdx.x;
    const float* fp = feats + (size_t)b * NBLK * NFEAT;
    for (int i = tid; i < NBLK * NFEAT; i += 256) F[i / NFEAT][i % NFEAT] = fp[i];
    __syncthreads();
    if (tid < NFEAT) {
        double s = 0.0;
        for (int n = 0; n < NBLK; ++n) s += (double)F[n][tid];
        mu[tid] = s / (double)NBLK;
        dff[tid] = (double)mu_pris[tid] - mu[tid];
    }
    __syncthreads();
    for (int e = tid; e < NFEAT * NFEAT; e += 256) {
        int f = e / NFEAT, g = e % NFEAT;
        double mf = mu[f], mg = mu[g];
        double s = 0.0;
        for (int n = 0; n < NBLK; ++n) s += ((double)F[n][f] - mf) * ((double)F[n][g] - mg);
        A[f][g] = (s / (double)(NBLK - 1) + (double)cov_pris[f * NFEAT + g]) * 0.5;
    }
    if (tid < NFEAT) A[tid][NFEAT] = dff[tid];
    for (int k = 0; k < NFEAT - 1; ++k) {
        __syncthreads();
        double rk = 1.0 / A[k][k];
        for (int e = tid; e < NFEAT * (NFEAT + 1); e += 256) {
            int r = e / (NFEAT + 1), c = e % (NFEAT + 1);
            if (r > k && c > k) A[r][c] -= (A[r][k] * rk) * A[k][c];
        }
    }
    __syncthreads();
    for (int i = NFEAT - 1; i >= 0; --i) {
        if (tid == i) xs[i] = A[i][NFEAT] / A[i][i];
        __syncthreads();
        if (tid < i) A[tid][NFEAT] -= A[tid][i] * xs[i];
    }
    __syncthreads();
    if (tid == 0) {
        double quad = 0.0;
        for (int i = 0; i < NFEAT; ++i) quad += dff[i] * xs[i];
        out[b] = (float)sqrt(fmax(quad, 0.0));
    }
}

// ---------------- launch ----------------
extern "C" void kernel_launch(void* const* d_in, const int* in_sizes, int n_in,
                              void* d_out, int out_size, void* d_ws, size_t ws_size,
                              hipStream_t stream) {
    const float* img      = (const float*)d_in[0];
    const float* mu_pris  = (const float*)d_in[1];
    const float* cov_pris = (const float*)d_in[2];
    float* out = (float*)d_out;
    float* ws = (float*)d_ws;

    float* rgam  = ws;                 // 9801 (pad to 9856)
    float* convt = rgam + 9856;
    float* meanf = convt + 9856;
    float* w1d   = meanf + 9856;       // 8
    float* stats1 = w1d + 8;                           // 16*121*25
    float* stats2 = stats1 + BATCH * NBLK * 25;
    float* feats  = stats2 + BATCH * NBLK * 25;        // 16*121*36
    float* dsimg  = feats + BATCH * NBLK * NFEAT;      // 16*528*528

    init_tables<<<(NGRID + 255) / 256, 256, 0, stream>>>(rgam, convt, meanf, w1d);

    fused_mscn_stats<96, true><<<dim3(NBLK, BATCH), 512, 0, stream>>>(
        img, dsimg, w1d, stats1);
    fused_mscn_stats<48, false><<<dim3(NBLK, BATCH), 256, 0, stream>>>(
        dsimg, nullptr, w1d, stats2);

    aggd_kernel<<<(2 * BATCH * NBLK * 5 + 255) / 256, 256, 0, stream>>>(
        stats1, stats2, rgam, convt, meanf, feats);

    score_kernel<<<BATCH, 256, 0, stream>>>(feats, mu_pris, cov_pris, out);
}

// Round 9
// 190.171 us; speedup vs baseline: 1.3556x; 1.3556x over previous
//
#include <hip/hip_runtime.h>
#include <math.h>

#define NGRID 9801
#define NB 11            // blocks per dim (both scales)
#define NBLK (NB*NB)     // 121
#define BATCH 16
#define NFEAT 36

// ---------------- tables ----------------
__global__ void init_tables(float* __restrict__ rgam, float* __restrict__ convt,
                            float* __restrict__ meanf, float* __restrict__ w1d) {
    int i = blockIdx.x * blockDim.x + threadIdx.x;
    if (i < NGRID) {
        double a = (double)(float)(0.2 + 0.001 * (double)i);  // match float32 grid
        double g1 = lgamma(1.0 / a);
        double g2 = lgamma(2.0 / a);
        double g3 = lgamma(3.0 / a);
        rgam[i]  = (float)exp(2.0 * g2 - g1 - g3);
        convt[i] = (float)sqrt(exp(g1 - g3));
        meanf[i] = (float)exp(g2 - g1);
    }
    if (i == 0) {
        double g[7], s = 0.0;
        for (int k = 0; k < 7; ++k) { double d = (double)(k - 3); g[k] = exp(-d * d * 18.0 / 49.0); s += g[k]; }
        for (int k = 0; k < 7; ++k) w1d[k] = (float)(g[k] / s);
    }
}

__device__ __forceinline__ float bperm(int addr, float v) {
    return __int_as_float(__builtin_amdgcn_ds_bpermute(addr, __float_as_int(v)));
}

// ---------------- fused MSCN + in-register per-block stats (pipelined) --------
// One WG per (NIQE block, batch).
//   K=96: 2 slabs(48 cols) x 4 strips(24 rows) = 8 waves (512 thr).
//   K=48: 1 slab x 4 strips(12 rows) = 4 waves (256 thr).
// Round-6 body (VGPR ~56) with deeper (2-row) global prefetch; only the
// strip count / wave count changed. Seam handling is NSTRIP-agnostic:
//   - same-row cross-slab products: col-seam fixup (all rows)
//   - prev-row products within strip: walk (+ col-seam r>0)
//   - prev-row across strip boundary (incl. block wrap): row-seam fixup
template <int K, bool WDS>
__global__ __launch_bounds__(K == 96 ? 512 : 256) void fused_mscn_stats(
        const float* __restrict__ img, float* __restrict__ dsout,
        const float* __restrict__ w1d, float* __restrict__ stats) {
    constexpr int NSLAB = K / 48;
    constexpr int NSTRIP = 4;
    constexpr int WAVES = NSLAB * NSTRIP;
    constexpr int SROWS = K / NSTRIP;
    constexpr int W = K * NB;
    constexpr int H = W;

    __shared__ float lastrow[NSTRIP][K];            // each strip's last norm row
    __shared__ float edgeL[NSTRIP][NSLAB][SROWS];   // per-row slab-edge norm (K=96)
    __shared__ float edgeR[NSTRIP][NSLAB][SROWS];
    __shared__ float redf[WAVES][15];
    __shared__ float redc[WAVES][10];

    const int tid = threadIdx.x;
    const int lane = tid & 63;
    const int wv = tid >> 6;
    const int slab = wv % NSLAB;
    const int strip = wv / NSLAB;
    const int bIdx = blockIdx.x;
    const int b = blockIdx.y;
    const int bh = bIdx / NB, bw = bIdx % NB;
    const int x0 = bw * K + slab * 48;
    const int gx = x0 - 3 + lane;
    const int gxc = min(max(gx, 0), W - 1);
    const int r0 = bh * K + strip * SROWS;
    const int basem3 = (lane - 3) << 2;
    const bool act = (lane >= 3) && (lane <= 50);
    int am1, ap1;
    if constexpr (NSLAB == 1) {
        am1 = ((lane == 3) ? 50 : (lane - 1)) << 2;
        ap1 = ((lane == 50) ? 3 : (lane + 1)) << 2;
    } else {
        am1 = ((lane - 1) & 63) << 2;   // lane3 reads zeroed lane2 -> fixup later
        ap1 = ((lane + 1) & 63) << 2;   // lane50 reads zeroed lane51 -> fixup later
    }

    const float* im = img + (size_t)b * H * W + gxc;
    const float w0=w1d[0], w1=w1d[1], w2=w1d[2], w3=w1d[3], w4=w1d[4], w5=w1d[5], w6=w1d[6];

    auto ld = [&](int r) -> float {
        int rc = min(max(r, 0), H - 1);
        return im[(size_t)rc * W];
    };

    float pa0, pa1, pa2, pa4, pa5, pa6, vHp;
    auto issue_raw = [&](float v) {
        pa0 = bperm(basem3,      v);
        pa1 = bperm(basem3 + 4,  v);
        pa2 = bperm(basem3 + 8,  v);
        pa4 = bperm(basem3 + 16, v);
        pa5 = bperm(basem3 + 20, v);
        pa6 = bperm(basem3 + 24, v);
        vHp = v;
    };
    auto combine_raw = [&](float& om, float& oq) {
        om = ((w0*pa0 + w1*pa1) + (w2*pa2 + w3*vHp)) + ((w4*pa4 + w5*pa5) + w6*pa6);
        oq = ((w0*pa0*pa0 + w1*pa1*pa1) + (w2*pa2*pa2 + w3*vHp*vHp))
           + ((w4*pa4*pa4 + w5*pa5*pa5) + w6*pa6*pa6);
    };

    float acc[5][3];
    #pragma unroll
    for (int s = 0; s < 5; ++s) { acc[s][0] = acc[s][1] = acc[s][2] = 0.f; }
    int cl[5] = {0,0,0,0,0}, cr[5] = {0,0,0,0,0};

    auto upd = [&](int s, float v) {
        float vp = fmaxf(v, 0.f);
        acc[s][0] = fmaf(vp, vp, acc[s][0]);   // sr2
        acc[s][1] = fmaf(v, v, acc[s][1]);     // ssq (sl2 = ssq - sr2 later)
        acc[s][2] += fabsf(v);                 // sum |v|
        cl[s] += __popcll(__ballot(v < 0.f));  // scalar-unit counts
        cr[s] += __popcll(__ballot(v > 0.f));
    };

    // prologue: fill 7-row hconv ring (rows r0-3 .. r0+3) + pend row r0+4
    float mr0,mr1,mr2,mr3,mr4,mr5,mr6, qr0,qr1,qr2,qr3,qr4,qr5,qr6;
    float rA, rB, rC, rD;
    float vN = ld(r0 - 3);
    { float v=vN; vN=ld(r0-2); issue_raw(v); combine_raw(mr0,qr0); }
    { float v=vN; vN=ld(r0-1); issue_raw(v); combine_raw(mr1,qr1); }
    { float v=vN; vN=ld(r0+0); issue_raw(v); combine_raw(mr2,qr2); }
    { float v=vN; vN=ld(r0+1); issue_raw(v); combine_raw(mr3,qr3); rA=v; }
    { float v=vN; vN=ld(r0+2); issue_raw(v); combine_raw(mr4,qr4); rB=v; }
    { float v=vN; vN=ld(r0+3); issue_raw(v); combine_raw(mr5,qr5); rC=v; }
    { float v=vN; vN=ld(r0+4); issue_raw(v); combine_raw(mr6,qr6); rD=v; }
    { float v=vN; vN=ld(r0+5); issue_raw(v); }   // pends = row r0+4
    float vN2 = ld(r0 + 6);                      // 2-deep prefetch

    float normP = 0.f, normP2 = 0.f;
    float pendSL = 0.f, pendPL = 0.f, pendPR = 0.f;
    float firstN = 0.f, dsSave = 0.f;
    const bool dsw = WDS && (lane & 1) && (lane >= 3) && (lane <= 49);

    #pragma unroll 4
    for (int yy = 0; yy < SROWS; ++yy) {
        const int y = r0 + yy;
        // 1) stats for row y-1 (pure VALU; pend bperms issued last iter)
        if (yy > 0) {
            upd(0, normP);
            upd(1, normP * pendSL);
            upd(2, normP * normP2);
            upd(3, normP * pendPL);
            upd(4, normP * pendPR);
        }
        // 2) vertical combine for row y (ring ready since last iter)
        float mu = ((w0*mr0 + w1*mr1) + (w2*mr2 + w3*mr3)) + ((w4*mr4 + w5*mr5) + w6*mr6);
        float s2 = ((w0*qr0 + w1*qr1) + (w2*qr2 + w3*qr3)) + ((w4*qr4 + w5*qr5) + w6*qr6);
        float sig = __builtin_amdgcn_sqrtf(fabsf(s2 - mu * mu));
        float nrm = (rA - mu) * __builtin_amdgcn_rcpf(sig + 1.0f);
        float cur = act ? nrm : 0.f;

        // 3) captures
        if (yy == 0) firstN = cur;
        if constexpr (NSLAB == 2) {
            if (lane == 3)  edgeL[strip][slab][yy] = cur;
            if (lane == 50) edgeR[strip][slab][yy] = cur;
        }
        if (yy == SROWS - 1 && act) lastrow[strip][slab * 48 + lane - 3] = cur;

        // 4) fused 2x2-mean downsample of raw input
        if constexpr (WDS) {
            float hs = rA + __shfl_down(rA, 1);
            if ((y & 1) == 0) dsSave = hs;
            else if (dsw)
                dsout[((size_t)b * (H / 2) + (y >> 1)) * (W / 2) + (gx >> 1)] = 0.25f * (dsSave + hs);
        }

        // 5) issue product bperms for next iteration's stats
        pendSL = bperm(am1, cur);
        pendPL = bperm(am1, normP);
        pendPR = bperm(ap1, normP);
        normP2 = normP; normP = cur;

        // 6) hconv combine for row y+4 (pends issued last iter) + ring shift
        float mh, qh; combine_raw(mh, qh);
        mr0=mr1; mr1=mr2; mr2=mr3; mr3=mr4; mr4=mr5; mr5=mr6; mr6=mh;
        qr0=qr1; qr1=qr2; qr2=qr3; qr3=qr4; qr4=qr5; qr5=qr6; qr6=qh;

        // 7) raw ring shift, issue next raw bperms, rotate 2-deep prefetch
        rA=rB; rB=rC; rC=rD; rD=vHp;
        float vv = vN; vN = vN2; vN2 = ld(y + 7);
        issue_raw(vv);
    }
    // epilogue: stats for the strip's last row
    upd(0, normP);
    upd(1, normP * pendSL);
    upd(2, normP * normP2);
    upd(3, normP * pendPL);
    upd(4, normP * pendPR);

    __syncthreads();

    // ---- row-seam fixup: products of row r0 with block-circular previous row ----
    {
        const int ps = (strip + NSTRIP - 1) % NSTRIP;
        int j  = slab * 48 + (lane - 3);
        int js = act ? j : 0;
        int jm1 = (js + K - 1) % K;
        int jp1 = (js + 1) % K;
        float pv  = act ? lastrow[ps][js]  : 0.f;
        float pvL = act ? lastrow[ps][jm1] : 0.f;
        float pvR = act ? lastrow[ps][jp1] : 0.f;
        upd(2, firstN * pv);
        upd(3, firstN * pvL);
        upd(4, firstN * pvR);
    }

    // ---- column-seam fixup (K=96 only): slab-edge wrap products ----
    if constexpr (NSLAB == 2) {
        if (lane < SROWS) {
            int r = lane;
            if (slab == 0) {
                float c0  = edgeL[strip][0][r];   // n[r][0]
                float e95 = edgeR[strip][1][r];   // n[r][95]
                upd(1, c0 * e95);
                if (r > 0) {
                    upd(3, c0 * edgeR[strip][1][r - 1]);
                    upd(4, edgeR[strip][0][r] * edgeL[strip][1][r - 1]);  // col47 * n[r-1][48]
                }
            } else {
                float c48 = edgeL[strip][1][r];   // n[r][48]
                float e47 = edgeR[strip][0][r];   // n[r][47]
                upd(1, c48 * e47);
                if (r > 0) {
                    upd(3, c48 * edgeR[strip][0][r - 1]);
                    upd(4, edgeR[strip][1][r] * edgeL[strip][0][r - 1]); // col95 * n[r-1][0]
                }
            }
        }
    }

    // ---- reduce: 15 floats via shuffles; counts are wave-uniform scalars ----
    #pragma unroll
    for (int off = 32; off >= 1; off >>= 1)
        #pragma unroll
        for (int s = 0; s < 5; ++s) {
            acc[s][0] += __shfl_down(acc[s][0], off);
            acc[s][1] += __shfl_down(acc[s][1], off);
            acc[s][2] += __shfl_down(acc[s][2], off);
        }
    if (lane == 0) {
        #pragma unroll
        for (int s = 0; s < 5; ++s) {
            redf[wv][s*3+0] = acc[s][0];
            redf[wv][s*3+1] = acc[s][1];
            redf[wv][s*3+2] = acc[s][2];
            redc[wv][s*2+0] = (float)cl[s];
            redc[wv][s*2+1] = (float)cr[s];
        }
    }
    __syncthreads();
    if (tid < 15) {
        float s = 0.f;
        #pragma unroll
        for (int w = 0; w < WAVES; ++w) s += redf[w][tid];
        stats[((size_t)b * NBLK + bIdx) * 25 + tid] = s;
    } else if (tid < 25) {
        int t = tid - 15;
        float s = 0.f;
        #pragma unroll
        for (int w = 0; w < WAVES; ++w) s += redc[w][t];
        stats[((size_t)b * NBLK + bIdx) * 25 + tid] = s;
    }
}

// ---------------- AGGD closed-form + binary-search argmin ----------------
__global__ __launch_bounds__(256) void aggd_kernel(
        const float* __restrict__ stats1, const float* __restrict__ stats2,
        const float* __restrict__ rgam, const float* __restrict__ convt,
        const float* __restrict__ meanf, float* __restrict__ feats) {
    __shared__ float rg[NGRID];
    for (int i = threadIdx.x; i < NGRID; i += 256) rg[i] = rgam[i];
    __syncthreads();

    int gid = blockIdx.x * 256 + threadIdx.x;
    if (gid >= 2 * BATCH * NBLK * 5) return;
    int s = gid % 5; int t = gid / 5;
    int blk = t % NBLK; t /= NBLK;
    int b = t % BATCH; int scale = t / BATCH;

    const float* st = (scale ? stats2 : stats1) + ((size_t)b * NBLK + blk) * 25;
    float sr2 = st[s*3+0], ssq = st[s*3+1], sab = st[s*3+2];
    float cl = st[15 + 2*s], cr = st[15 + 2*s + 1];
    float sl2 = fmaxf(ssq - sr2, 0.f);
    float n = scale ? (48.f * 48.f) : (96.f * 96.f);

    float lstd = sqrtf(sl2 / (cl + 1e-8f));
    float rstd = sqrtf(sr2 / (cr + 1e-8f));
    float gh = lstd / rstd;
    float mab = sab / n;
    float msq = ssq / n;
    float rhat = mab * mab / msq;
    float g2 = gh * gh;
    float x = rhat * (gh * g2 + 1.f) * (gh + 1.f) / ((g2 + 1.f) * (g2 + 1.f));

    int lo = 0, hi = NGRID;
    while (lo < hi) {
        int mid = (lo + hi) >> 1;
        if (rg[mid] < x) lo = mid + 1; else hi = mid;
    }
    int gi;
    if (lo <= 0) gi = 0;
    else if (lo >= NGRID) gi = NGRID - 1;
    else {
        float dlo = x - rg[lo - 1];
        float dhi = rg[lo] - x;
        gi = (dlo <= dhi) ? lo - 1 : lo;   // tie -> lower index (first-min)
    }

    float alpha = (float)(0.2 + 0.001 * (double)gi);
    float cv = convt[gi];
    float lb = lstd * cv, rb = rstd * cv;
    float* fo = feats + ((size_t)b * NBLK + blk) * NFEAT + (scale ? 18 : 0);
    if (s == 0) {
        fo[0] = alpha;
        fo[1] = 0.5f * (lb + rb);
    } else {
        int o = 2 + (s - 1) * 4;
        fo[o]     = alpha;
        fo[o + 1] = (rb - lb) * meanf[gi];
        fo[o + 2] = lb;
        fo[o + 3] = rb;
    }
}

// ---------------- per-batch covariance + solve + score ----------------
__global__ __launch_bounds__(256) void score_kernel(
        const float* __restrict__ feats, const float* __restrict__ mu_pris,
        const float* __restrict__ cov_pris, float* __restrict__ out) {
    __shared__ float F[NBLK][NFEAT];
    __shared__ double mu[NFEAT];
    __shared__ double A[NFEAT][NFEAT + 1];
    __shared__ double dff[NFEAT];
    __shared__ double xs[NFEAT];
    int b = blockIdx.x, tid = threadIdx.x;
    const float* fp = feats + (size_t)b * NBLK * NFEAT;
    for (int i = tid; i < NBLK * NFEAT; i += 256) F[i / NFEAT][i % NFEAT] = fp[i];
    __syncthreads();
    if (tid < NFEAT) {
        double s = 0.0;
        for (int n = 0; n < NBLK; ++n) s += (double)F[n][tid];
        mu[tid] = s / (double)NBLK;
        dff[tid] = (double)mu_pris[tid] - mu[tid];
    }
    __syncthreads();
    for (int e = tid; e < NFEAT * NFEAT; e += 256) {
        int f = e / NFEAT, g = e % NFEAT;
        double mf = mu[f], mg = mu[g];
        double s = 0.0;
        for (int n = 0; n < NBLK; ++n) s += ((double)F[n][f] - mf) * ((double)F[n][g] - mg);
        A[f][g] = (s / (double)(NBLK - 1) + (double)cov_pris[f * NFEAT + g]) * 0.5;
    }
    if (tid < NFEAT) A[tid][NFEAT] = dff[tid];
    for (int k = 0; k < NFEAT - 1; ++k) {
        __syncthreads();
        double rk = 1.0 / A[k][k];
        for (int e = tid; e < NFEAT * (NFEAT + 1); e += 256) {
            int r = e / (NFEAT + 1), c = e % (NFEAT + 1);
            if (r > k && c > k) A[r][c] -= (A[r][k] * rk) * A[k][c];
        }
    }
    __syncthreads();
    for (int i = NFEAT - 1; i >= 0; --i) {
        if (tid == i) xs[i] = A[i][NFEAT] / A[i][i];
        __syncthreads();
        if (tid < i) A[tid][NFEAT] -= A[tid][i] * xs[i];
    }
    __syncthreads();
    if (tid == 0) {
        double quad = 0.0;
        for (int i = 0; i < NFEAT; ++i) quad += dff[i] * xs[i];
        out[b] = (float)sqrt(fmax(quad, 0.0));
    }
}

// ---------------- launch ----------------
extern "C" void kernel_launch(void* const* d_in, const int* in_sizes, int n_in,
                              void* d_out, int out_size, void* d_ws, size_t ws_size,
                              hipStream_t stream) {
    const float* img      = (const float*)d_in[0];
    const float* mu_pris  = (const float*)d_in[1];
    const float* cov_pris = (const float*)d_in[2];
    float* out = (float*)d_out;
    float* ws = (float*)d_ws;

    float* rgam  = ws;                 // 9801 (pad to 9856)
    float* convt = rgam + 9856;
    float* meanf = convt + 9856;
    float* w1d   = meanf + 9856;       // 8
    float* stats1 = w1d + 8;                           // 16*121*25
    float* stats2 = stats1 + BATCH * NBLK * 25;
    float* feats  = stats2 + BATCH * NBLK * 25;        // 16*121*36
    float* dsimg  = feats + BATCH * NBLK * NFEAT;      // 16*528*528

    init_tables<<<(NGRID + 255) / 256, 256, 0, stream>>>(rgam, convt, meanf, w1d);

    fused_mscn_stats<96, true><<<dim3(NBLK, BATCH), 512, 0, stream>>>(
        img, dsimg, w1d, stats1);
    fused_mscn_stats<48, false><<<dim3(NBLK, BATCH), 256, 0, stream>>>(
        dsimg, nullptr, w1d, stats2);

    aggd_kernel<<<(2 * BATCH * NBLK * 5 + 255) / 256, 256, 0, stream>>>(
        stats1, stats2, rgam, convt, meanf, feats);

    score_kernel<<<BATCH, 256, 0, stream>>>(feats, mu_pris, cov_pris, out);
}

// Round 10
// 174.303 us; speedup vs baseline: 1.4790x; 1.0910x over previous
//
#include <hip/hip_runtime.h>
#include <math.h>

#define NGRID 9801
#define NB 11            // blocks per dim (both scales)
#define NBLK (NB*NB)     // 121
#define BATCH 16
#define NFEAT 36

// ---------------- tables ----------------
__global__ void init_tables(float* __restrict__ rgam, float* __restrict__ convt,
                            float* __restrict__ meanf, float* __restrict__ w1d) {
    int i = blockIdx.x * blockDim.x + threadIdx.x;
    if (i < NGRID) {
        double a = (double)(float)(0.2 + 0.001 * (double)i);  // match float32 grid
        double g1 = lgamma(1.0 / a);
        double g2 = lgamma(2.0 / a);
        double g3 = lgamma(3.0 / a);
        rgam[i]  = (float)exp(2.0 * g2 - g1 - g3);
        convt[i] = (float)sqrt(exp(g1 - g3));
        meanf[i] = (float)exp(g2 - g1);
    }
    if (i == 0) {
        double g[7], s = 0.0;
        for (int k = 0; k < 7; ++k) { double d = (double)(k - 3); g[k] = exp(-d * d * 18.0 / 49.0); s += g[k]; }
        for (int k = 0; k < 7; ++k) w1d[k] = (float)(g[k] / s);
    }
}

__device__ __forceinline__ float bperm(int addr, float v) {
    return __int_as_float(__builtin_amdgcn_ds_bpermute(addr, __float_as_int(v)));
}

// ---------------- fused MSCN + in-register per-block stats (pipelined) --------
// One WG per (NIQE block, batch). Round-6 structure:
//   K=96: 2 slabs(48 cols) x 2 strips(48 rows) = 4 waves (256 thr).
//   K=48: 1 slab x 4 strips(12 rows) = 4 waves (256 thr).
// Deltas vs round 6: (a) incremental 32-bit load addressing with SALU-uniform
// clamped delta; (b) cl/cr counts from 2 ballots/row + scalar mask algebra
// (zero-product exclusion preserved via nz masks); (c) 2-deep load prefetch.
template <int K, bool WDS>
__global__ __launch_bounds__(256) void fused_mscn_stats(
        const float* __restrict__ img, float* __restrict__ dsout,
        const float* __restrict__ w1d, float* __restrict__ stats) {
    constexpr int NSLAB = K / 48;
    constexpr int NSTRIP = 4 / NSLAB;
    constexpr int SROWS = K / NSTRIP;
    constexpr int W = K * NB;
    constexpr int H = W;

    __shared__ float lastrow[NSTRIP][K];            // each strip's last norm row
    __shared__ float edgeL[NSTRIP][NSLAB][SROWS];   // per-row slab-edge norm (K=96)
    __shared__ float edgeR[NSTRIP][NSLAB][SROWS];
    __shared__ float redf[4][15];
    __shared__ float redc[4][10];

    const int tid = threadIdx.x;
    const int lane = tid & 63;
    const int wv = tid >> 6;
    const int slab = wv % NSLAB;
    const int strip = wv / NSLAB;
    const int bIdx = blockIdx.x;
    const int b = blockIdx.y;
    const int bh = bIdx / NB, bw = bIdx % NB;
    const int x0 = bw * K + slab * 48;
    const int gx = x0 - 3 + lane;
    const int gxc = min(max(gx, 0), W - 1);
    const int r0 = bh * K + strip * SROWS;
    const int basem3 = (lane - 3) << 2;
    const bool act = (lane >= 3) && (lane <= 50);
    int am1, ap1;
    if constexpr (NSLAB == 1) {
        am1 = ((lane == 3) ? 50 : (lane - 1)) << 2;
        ap1 = ((lane == 50) ? 3 : (lane + 1)) << 2;
    } else {
        am1 = ((lane - 1) & 63) << 2;   // lane3 reads zeroed lane2 -> fixup later
        ap1 = ((lane + 1) & 63) << 2;   // lane50 reads zeroed lane51 -> fixup later
    }

    const char* baseB = (const char*)(img + (size_t)b * H * W);
    const float w0=w1d[0], w1=w1d[1], w2=w1d[2], w3=w1d[3], w4=w1d[4], w5=w1d[5], w6=w1d[6];

    // incremental addressing: per-lane byte offset + uniform clamped delta
    int addrB = (min(max(r0 - 3, 0), H - 1) * W + gxc) * 4;
    int rowNext = r0 - 2;                  // uniform: row index of NEXT load
    auto ld = [&]() -> float {
        float v = *(const float*)(baseB + addrB);
        addrB += (rowNext >= 1 && rowNext < H) ? (W * 4) : 0;  // uniform SALU
        ++rowNext;
        return v;
    };

    float pa0, pa1, pa2, pa4, pa5, pa6, vHp;
    auto issue_raw = [&](float v) {
        pa0 = bperm(basem3,      v);
        pa1 = bperm(basem3 + 4,  v);
        pa2 = bperm(basem3 + 8,  v);
        pa4 = bperm(basem3 + 16, v);
        pa5 = bperm(basem3 + 20, v);
        pa6 = bperm(basem3 + 24, v);
        vHp = v;
    };
    auto combine_raw = [&](float& om, float& oq) {
        om = ((w0*pa0 + w1*pa1) + (w2*pa2 + w3*vHp)) + ((w4*pa4 + w5*pa5) + w6*pa6);
        oq = ((w0*pa0*pa0 + w1*pa1*pa1) + (w2*pa2*pa2 + w3*vHp*vHp))
           + ((w4*pa4*pa4 + w5*pa5*pa5) + w6*pa6*pa6);
    };

    float acc[5][3];
    #pragma unroll
    for (int s = 0; s < 5; ++s) { acc[s][0] = acc[s][1] = acc[s][2] = 0.f; }
    int cl[5] = {0,0,0,0,0}, cr[5] = {0,0,0,0,0};

    // full upd (ballot-counted) -- used only in low-frequency seam fixups
    auto upd = [&](int s, float v) {
        float vp = fmaxf(v, 0.f);
        acc[s][0] = fmaf(vp, vp, acc[s][0]);   // sr2
        acc[s][1] = fmaf(v, v, acc[s][1]);     // ssq (sl2 = ssq - sr2 later)
        acc[s][2] += fabsf(v);                 // sum |v|
        cl[s] += __popcll(__ballot(v < 0.f));
        cr[s] += __popcll(__ballot(v > 0.f));
    };
    // value-only update for the hot loop (counts via scalar masks)
    auto updv = [&](int s, float v) {
        float vp = fmaxf(v, 0.f);
        acc[s][0] = fmaf(vp, vp, acc[s][0]);
        acc[s][1] = fmaf(v, v, acc[s][1]);
        acc[s][2] += fabsf(v);
    };

    // sign-mask state: A = row normP, B = row normP2
    unsigned long long mA = 0, pA = 0, nzA = 0, mB = 0, nzB = 0;
    auto shl1 = [&](unsigned long long x) -> unsigned long long {
        if constexpr (NSLAB == 1) {
            unsigned long long w = (x >> 3) & 0xFFFFFFFFFFFFULL;   // 48-bit window
            w = ((w << 1) | (w >> 47)) & 0xFFFFFFFFFFFFULL;        // circular
            return w << 3;
        } else return x << 1;
    };
    auto shr1 = [&](unsigned long long x) -> unsigned long long {
        if constexpr (NSLAB == 1) {
            unsigned long long w = (x >> 3) & 0xFFFFFFFFFFFFULL;
            w = ((w >> 1) | (w << 47)) & 0xFFFFFFFFFFFFULL;
            return w << 3;
        } else return x >> 1;
    };
    auto count_row = [&]() {   // counts for row A (normP) vs row B (normP2)
        cl[0] += __popcll(mA); cr[0] += __popcll(pA);
        { unsigned long long x = mA ^ shl1(mA), v = nzA & shl1(nzA);
          int n = __popcll(x & v); cl[1] += n; cr[1] += __popcll(v) - n; }
        { unsigned long long x = mA ^ mB, v = nzA & nzB;
          int n = __popcll(x & v); cl[2] += n; cr[2] += __popcll(v) - n; }
        { unsigned long long x = mA ^ shl1(mB), v = nzA & shl1(nzB);
          int n = __popcll(x & v); cl[3] += n; cr[3] += __popcll(v) - n; }
        { unsigned long long x = mA ^ shr1(mB), v = nzA & shr1(nzB);
          int n = __popcll(x & v); cl[4] += n; cr[4] += __popcll(v) - n; }
    };

    // prologue: fill 7-row hconv ring (rows r0-3 .. r0+3) + pend row r0+4
    float mr0,mr1,mr2,mr3,mr4,mr5,mr6, qr0,qr1,qr2,qr3,qr4,qr5,qr6;
    float rA, rB, rC, rD;
    float vN = ld();
    { float v=vN; vN=ld(); issue_raw(v); combine_raw(mr0,qr0); }
    { float v=vN; vN=ld(); issue_raw(v); combine_raw(mr1,qr1); }
    { float v=vN; vN=ld(); issue_raw(v); combine_raw(mr2,qr2); }
    { float v=vN; vN=ld(); issue_raw(v); combine_raw(mr3,qr3); rA=v; }
    { float v=vN; vN=ld(); issue_raw(v); combine_raw(mr4,qr4); rB=v; }
    { float v=vN; vN=ld(); issue_raw(v); combine_raw(mr5,qr5); rC=v; }
    { float v=vN; vN=ld(); issue_raw(v); combine_raw(mr6,qr6); rD=v; }
    { float v=vN; vN=ld(); issue_raw(v); }   // pends = row r0+4
    float vN2 = ld();                        // 2-deep prefetch (row r0+6)

    float normP = 0.f, normP2 = 0.f;
    float pendSL = 0.f, pendPL = 0.f, pendPR = 0.f;
    float firstN = 0.f, dsSave = 0.f;
    const bool dsw = WDS && (lane & 1) && (lane >= 3) && (lane <= 49);

    #pragma unroll 4
    for (int yy = 0; yy < SROWS; ++yy) {
        const int y = r0 + yy;
        // 1) stats for row y-1 (pure VALU + SALU counts)
        if (yy > 0) {
            updv(0, normP);
            updv(1, normP * pendSL);
            updv(2, normP * normP2);
            updv(3, normP * pendPL);
            updv(4, normP * pendPR);
            count_row();
        }
        // 2) vertical combine for row y (ring ready since last iter)
        float mu = ((w0*mr0 + w1*mr1) + (w2*mr2 + w3*mr3)) + ((w4*mr4 + w5*mr5) + w6*mr6);
        float s2 = ((w0*qr0 + w1*qr1) + (w2*qr2 + w3*qr3)) + ((w4*qr4 + w5*qr5) + w6*qr6);
        float sig = __builtin_amdgcn_sqrtf(fabsf(s2 - mu * mu));
        float nrm = (rA - mu) * __builtin_amdgcn_rcpf(sig + 1.0f);
        float cur = act ? nrm : 0.f;

        // 3) captures
        if (yy == 0) firstN = cur;
        if constexpr (NSLAB == 2) {
            if (lane == 3)  edgeL[strip][slab][yy] = cur;
            if (lane == 50) edgeR[strip][slab][yy] = cur;
        }
        if (yy == SROWS - 1 && act) lastrow[strip][slab * 48 + lane - 3] = cur;

        // 4) fused 2x2-mean downsample of raw input
        if constexpr (WDS) {
            float hs = rA + __shfl_down(rA, 1);
            if ((y & 1) == 0) dsSave = hs;
            else if (dsw)
                dsout[((size_t)b * (H / 2) + (y >> 1)) * (W / 2) + (gx >> 1)] = 0.25f * (dsSave + hs);
        }

        // 5) issue product bperms for next iteration's stats; rotate masks
        pendSL = bperm(am1, cur);
        pendPL = bperm(am1, normP);
        pendPR = bperm(ap1, normP);
        normP2 = normP; normP = cur;
        mB = mA; nzB = nzA;
        mA = __ballot(cur < 0.f);
        pA = __ballot(cur > 0.f);
        nzA = mA | pA;

        // 6) hconv combine for row y+4 (pends issued last iter) + ring shift
        float mh, qh; combine_raw(mh, qh);
        mr0=mr1; mr1=mr2; mr2=mr3; mr3=mr4; mr4=mr5; mr5=mr6; mr6=mh;
        qr0=qr1; qr1=qr2; qr2=qr3; qr3=qr4; qr4=qr5; qr5=qr6; qr6=qh;

        // 7) raw ring shift, issue next raw bperms, rotate 2-deep prefetch
        rA=rB; rB=rC; rC=rD; rD=vHp;
        float vv = vN; vN = vN2; vN2 = ld();
        issue_raw(vv);
    }
    // epilogue: stats for the strip's last row
    updv(0, normP);
    updv(1, normP * pendSL);
    updv(2, normP * normP2);
    updv(3, normP * pendPL);
    updv(4, normP * pendPR);
    count_row();

    __syncthreads();

    // ---- row-seam fixup: products of row r0 with block-circular previous row ----
    {
        const int ps = (strip + NSTRIP - 1) % NSTRIP;
        int j  = slab * 48 + (lane - 3);
        int js = act ? j : 0;
        int jm1 = (js + K - 1) % K;
        int jp1 = (js + 1) % K;
        float pv  = act ? lastrow[ps][js]  : 0.f;
        float pvL = act ? lastrow[ps][jm1] : 0.f;
        float pvR = act ? lastrow[ps][jp1] : 0.f;
        upd(2, firstN * pv);
        upd(3, firstN * pvL);
        upd(4, firstN * pvR);
    }

    // ---- column-seam fixup (K=96 only): slab-edge wrap products ----
    if constexpr (NSLAB == 2) {
        if (lane < SROWS) {
            int r = lane;
            if (slab == 0) {
                float c0  = edgeL[strip][0][r];   // n[r][0]
                float e95 = edgeR[strip][1][r];   // n[r][95]
                upd(1, c0 * e95);
                if (r > 0) {
                    upd(3, c0 * edgeR[strip][1][r - 1]);
                    upd(4, edgeR[strip][0][r] * edgeL[strip][1][r - 1]);  // col47 * n[r-1][48]
                }
            } else {
                float c48 = edgeL[strip][1][r];   // n[r][48]
                float e47 = edgeR[strip][0][r];   // n[r][47]
                upd(1, c48 * e47);
                if (r > 0) {
                    upd(3, c48 * edgeR[strip][0][r - 1]);
                    upd(4, edgeR[strip][1][r] * edgeL[strip][0][r - 1]); // col95 * n[r-1][0]
                }
            }
        }
    }

    // ---- reduce: 15 floats via shuffles; counts are wave-uniform scalars ----
    #pragma unroll
    for (int off = 32; off >= 1; off >>= 1)
        #pragma unroll
        for (int s = 0; s < 5; ++s) {
            acc[s][0] += __shfl_down(acc[s][0], off);
            acc[s][1] += __shfl_down(acc[s][1], off);
            acc[s][2] += __shfl_down(acc[s][2], off);
        }
    if (lane == 0) {
        #pragma unroll
        for (int s = 0; s < 5; ++s) {
            redf[wv][s*3+0] = acc[s][0];
            redf[wv][s*3+1] = acc[s][1];
            redf[wv][s*3+2] = acc[s][2];
            redc[wv][s*2+0] = (float)cl[s];
            redc[wv][s*2+1] = (float)cr[s];
        }
    }
    __syncthreads();
    if (tid < 15) {
        stats[((size_t)b * NBLK + bIdx) * 25 + tid] =
            redf[0][tid] + redf[1][tid] + redf[2][tid] + redf[3][tid];
    } else if (tid < 25) {
        int t = tid - 15;
        stats[((size_t)b * NBLK + bIdx) * 25 + tid] =
            redc[0][t] + redc[1][t] + redc[2][t] + redc[3][t];
    }
}

// ---------------- AGGD closed-form + binary-search argmin ----------------
__global__ __launch_bounds__(256) void aggd_kernel(
        const float* __restrict__ stats1, const float* __restrict__ stats2,
        const float* __restrict__ rgam, const float* __restrict__ convt,
        const float* __restrict__ meanf, float* __restrict__ feats) {
    __shared__ float rg[NGRID];
    for (int i = threadIdx.x; i < NGRID; i += 256) rg[i] = rgam[i];
    __syncthreads();

    int gid = blockIdx.x * 256 + threadIdx.x;
    if (gid >= 2 * BATCH * NBLK * 5) return;
    int s = gid % 5; int t = gid / 5;
    int blk = t % NBLK; t /= NBLK;
    int b = t % BATCH; int scale = t / BATCH;

    const float* st = (scale ? stats2 : stats1) + ((size_t)b * NBLK + blk) * 25;
    float sr2 = st[s*3+0], ssq = st[s*3+1], sab = st[s*3+2];
    float cl = st[15 + 2*s], cr = st[15 + 2*s + 1];
    float sl2 = fmaxf(ssq - sr2, 0.f);
    float n = scale ? (48.f * 48.f) : (96.f * 96.f);

    float lstd = sqrtf(sl2 / (cl + 1e-8f));
    float rstd = sqrtf(sr2 / (cr + 1e-8f));
    float gh = lstd / rstd;
    float mab = sab / n;
    float msq = ssq / n;
    float rhat = mab * mab / msq;
    float g2 = gh * gh;
    float x = rhat * (gh * g2 + 1.f) * (gh + 1.f) / ((g2 + 1.f) * (g2 + 1.f));

    int lo = 0, hi = NGRID;
    while (lo < hi) {
        int mid = (lo + hi) >> 1;
        if (rg[mid] < x) lo = mid + 1; else hi = mid;
    }
    int gi;
    if (lo <= 0) gi = 0;
    else if (lo >= NGRID) gi = NGRID - 1;
    else {
        float dlo = x - rg[lo - 1];
        float dhi = rg[lo] - x;
        gi = (dlo <= dhi) ? lo - 1 : lo;   // tie -> lower index (first-min)
    }

    float alpha = (float)(0.2 + 0.001 * (double)gi);
    float cv = convt[gi];
    float lb = lstd * cv, rb = rstd * cv;
    float* fo = feats + ((size_t)b * NBLK + blk) * NFEAT + (scale ? 18 : 0);
    if (s == 0) {
        fo[0] = alpha;
        fo[1] = 0.5f * (lb + rb);
    } else {
        int o = 2 + (s - 1) * 4;
        fo[o]     = alpha;
        fo[o + 1] = (rb - lb) * meanf[gi];
        fo[o + 2] = lb;
        fo[o + 3] = rb;
    }
}

// ---------------- per-batch covariance + solve + score ----------------
__global__ __launch_bounds__(256) void score_kernel(
        const float* __restrict__ feats, const float* __restrict__ mu_pris,
        const float* __restrict__ cov_pris, float* __restrict__ out) {
    __shared__ float F[NBLK][NFEAT];
    __shared__ double mu[NFEAT];
    __shared__ double A[NFEAT][NFEAT + 1];
    __shared__ double dff[NFEAT];
    __shared__ double xs[NFEAT];
    int b = blockIdx.x, tid = threadIdx.x;
    const float* fp = feats + (size_t)b * NBLK * NFEAT;
    for (int i = tid; i < NBLK * NFEAT; i += 256) F[i / NFEAT][i % NFEAT] = fp[i];
    __syncthreads();
    if (tid < NFEAT) {
        double s = 0.0;
        for (int n = 0; n < NBLK; ++n) s += (double)F[n][tid];
        mu[tid] = s / (double)NBLK;
        dff[tid] = (double)mu_pris[tid] - mu[tid];
    }
    __syncthreads();
    for (int e = tid; e < NFEAT * NFEAT; e += 256) {
        int f = e / NFEAT, g = e % NFEAT;
        double mf = mu[f], mg = mu[g];
        double s = 0.0;
        for (int n = 0; n < NBLK; ++n) s += ((double)F[n][f] - mf) * ((double)F[n][g] - mg);
        A[f][g] = (s / (double)(NBLK - 1) + (double)cov_pris[f * NFEAT + g]) * 0.5;
    }
    if (tid < NFEAT) A[tid][NFEAT] = dff[tid];
    for (int k = 0; k < NFEAT - 1; ++k) {
        __syncthreads();
        double rk = 1.0 / A[k][k];
        for (int e = tid; e < NFEAT * (NFEAT + 1); e += 256) {
            int r = e / (NFEAT + 1), c = e % (NFEAT + 1);
            if (r > k && c > k) A[r][c] -= (A[r][k] * rk) * A[k][c];
        }
    }
    __syncthreads();
    for (int i = NFEAT - 1; i >= 0; --i) {
        if (tid == i) xs[i] = A[i][NFEAT] / A[i][i];
        __syncthreads();
        if (tid < i) A[tid][NFEAT] -= A[tid][i] * xs[i];
    }
    __syncthreads();
    if (tid == 0) {
        double quad = 0.0;
        for (int i = 0; i < NFEAT; ++i) quad += dff[i] * xs[i];
        out[b] = (float)sqrt(fmax(quad, 0.0));
    }
}

// ---------------- launch ----------------
extern "C" void kernel_launch(void* const* d_in, const int* in_sizes, int n_in,
                              void* d_out, int out_size, void* d_ws, size_t ws_size,
                              hipStream_t stream) {
    const float* img      = (const float*)d_in[0];
    const float* mu_pris  = (const float*)d_in[1];
    const float* cov_pris = (const float*)d_in[2];
    float* out = (float*)d_out;
    float* ws = (float*)d_ws;

    float* rgam  = ws;                 // 9801 (pad to 9856)
    float* convt = rgam + 9856;
    float* meanf = convt + 9856;
    float* w1d   = meanf + 9856;       // 8
    float* stats1 = w1d + 8;                           // 16*121*25
    float* stats2 = stats1 + BATCH * NBLK * 25;
    float* feats  = stats2 + BATCH * NBLK * 25;        // 16*121*36
    float* dsimg  = feats + BATCH * NBLK * NFEAT;      // 16*528*528

    init_tables<<<(NGRID + 255) / 256, 256, 0, stream>>>(rgam, convt, meanf, w1d);

    fused_mscn_stats<96, true><<<dim3(NBLK, BATCH), 256, 0, stream>>>(
        img, dsimg, w1d, stats1);
    fused_mscn_stats<48, false><<<dim3(NBLK, BATCH), 256, 0, stream>>>(
        dsimg, nullptr, w1d, stats2);

    aggd_kernel<<<(2 * BATCH * NBLK * 5 + 255) / 256, 256, 0, stream>>>(
        stats1, stats2, rgam, convt, meanf, feats);

    score_kernel<<<BATCH, 256, 0, stream>>>(feats, mu_pris, cov_pris, out);
}

// Round 11
// 166.387 us; speedup vs baseline: 1.5493x; 1.0476x over previous
//
#include <hip/hip_runtime.h>
#include <math.h>

#define NGRID 9801
#define NB 11            // blocks per dim (both scales)
#define NBLK (NB*NB)     // 121
#define BATCH 16
#define NFEAT 36

// ---------------- tables ----------------
__global__ void init_tables(float* __restrict__ rgam, float* __restrict__ convt,
                            float* __restrict__ meanf, float* __restrict__ w1d) {
    int i = blockIdx.x * blockDim.x + threadIdx.x;
    if (i < NGRID) {
        double a = (double)(float)(0.2 + 0.001 * (double)i);  // match float32 grid
        double g1 = lgamma(1.0 / a);
        double g2 = lgamma(2.0 / a);
        double g3 = lgamma(3.0 / a);
        rgam[i]  = (float)exp(2.0 * g2 - g1 - g3);
        convt[i] = (float)sqrt(exp(g1 - g3));
        meanf[i] = (float)exp(g2 - g1);
    }
    if (i == 0) {
        double g[7], s = 0.0;
        for (int k = 0; k < 7; ++k) { double d = (double)(k - 3); g[k] = exp(-d * d * 18.0 / 49.0); s += g[k]; }
        for (int k = 0; k < 7; ++k) w1d[k] = (float)(g[k] / s);
    }
}

__device__ __forceinline__ float bperm(int addr, float v) {
    return __int_as_float(__builtin_amdgcn_ds_bpermute(addr, __float_as_int(v)));
}
// DPP wave shifts (VALU pipe, not DS). Semantics per LLVM AtomicOptimizer scan:
// ROW_SHR/WAVE_SHR: lane i <- lane i-1 (lane 0 -> 0 with bound_ctrl).
// WAVE_SHL: lane i <- lane i+1 (lane 63 -> 0).
__device__ __forceinline__ float dpp_getL(float v) {   // lane i <- lane i-1
    return __int_as_float(__builtin_amdgcn_update_dpp(
        0, __float_as_int(v), 0x138 /*WAVE_SHR1*/, 0xF, 0xF, true));
}
__device__ __forceinline__ float dpp_getR(float v) {   // lane i <- lane i+1
    return __int_as_float(__builtin_amdgcn_update_dpp(
        0, __float_as_int(v), 0x130 /*WAVE_SHL1*/, 0xF, 0xF, true));
}

// ---------------- fused MSCN + in-register per-block stats (pipelined) --------
// One WG per (NIQE block, batch). Round-10 structure:
//   K=96: 2 slabs(48 cols) x 2 strips(48 rows) = 4 waves (256 thr).
//   K=48: 1 slab x 4 strips(12 rows) = 4 waves (256 thr).
// Delta vs round 10: cross-lane shifts moved from ds_bpermute (DS pipe, which
// was ~90% saturated) to DPP wave shifts (VALU pipe). K=96 hot loop has ZERO
// DS ops; K=48 keeps 3 bpermutes for its circular product wrap.
template <int K, bool WDS>
__global__ __launch_bounds__(256) void fused_mscn_stats(
        const float* __restrict__ img, float* __restrict__ dsout,
        const float* __restrict__ w1d, float* __restrict__ stats) {
    constexpr int NSLAB = K / 48;
    constexpr int NSTRIP = 4 / NSLAB;
    constexpr int SROWS = K / NSTRIP;
    constexpr int W = K * NB;
    constexpr int H = W;

    __shared__ float lastrow[NSTRIP][K];            // each strip's last norm row
    __shared__ float edgeL[NSTRIP][NSLAB][SROWS];   // per-row slab-edge norm (K=96)
    __shared__ float edgeR[NSTRIP][NSLAB][SROWS];
    __shared__ float redf[4][15];
    __shared__ float redc[4][10];

    const int tid = threadIdx.x;
    const int lane = tid & 63;
    const int wv = tid >> 6;
    const int slab = wv % NSLAB;
    const int strip = wv / NSLAB;
    const int bIdx = blockIdx.x;
    const int b = blockIdx.y;
    const int bh = bIdx / NB, bw = bIdx % NB;
    const int x0 = bw * K + slab * 48;
    const int gx = x0 - 3 + lane;
    const int gxc = min(max(gx, 0), W - 1);
    const int r0 = bh * K + strip * SROWS;
    const bool act = (lane >= 3) && (lane <= 50);
    int am1 = 0, ap1 = 0;
    if constexpr (NSLAB == 1) {
        am1 = ((lane == 3) ? 50 : (lane - 1)) << 2;   // circular product wrap
        ap1 = ((lane == 50) ? 3 : (lane + 1)) << 2;
    }

    const char* baseB = (const char*)(img + (size_t)b * H * W);
    const float w0=w1d[0], w1=w1d[1], w2=w1d[2], w3=w1d[3], w4=w1d[4], w5=w1d[5], w6=w1d[6];

    // incremental addressing: per-lane byte offset + uniform clamped delta
    int addrB = (min(max(r0 - 3, 0), H - 1) * W + gxc) * 4;
    int rowNext = r0 - 2;                  // uniform: row index of NEXT load
    auto ld = [&]() -> float {
        float v = *(const float*)(baseB + addrB);
        addrB += (rowNext >= 1 && rowNext < H) ? (W * 4) : 0;  // uniform SALU
        ++rowNext;
        return v;
    };

    float pa0, pa1, pa2, pa4, pa5, pa6, vHp;
    auto issue_raw = [&](float v) {
        pa2 = dpp_getL(v);        // lane i-1
        pa1 = dpp_getL(pa2);      // lane i-2
        pa0 = dpp_getL(pa1);      // lane i-3
        pa4 = dpp_getR(v);        // lane i+1
        pa5 = dpp_getR(pa4);      // lane i+2
        pa6 = dpp_getR(pa5);      // lane i+3
        vHp = v;
    };
    auto combine_raw = [&](float& om, float& oq) {
        om = ((w0*pa0 + w1*pa1) + (w2*pa2 + w3*vHp)) + ((w4*pa4 + w5*pa5) + w6*pa6);
        oq = ((w0*pa0*pa0 + w1*pa1*pa1) + (w2*pa2*pa2 + w3*vHp*vHp))
           + ((w4*pa4*pa4 + w5*pa5*pa5) + w6*pa6*pa6);
    };

    float acc[5][3];
    #pragma unroll
    for (int s = 0; s < 5; ++s) { acc[s][0] = acc[s][1] = acc[s][2] = 0.f; }
    int cl[5] = {0,0,0,0,0}, cr[5] = {0,0,0,0,0};

    // full upd (ballot-counted) -- used only in low-frequency seam fixups
    auto upd = [&](int s, float v) {
        float vp = fmaxf(v, 0.f);
        acc[s][0] = fmaf(vp, vp, acc[s][0]);   // sr2
        acc[s][1] = fmaf(v, v, acc[s][1]);     // ssq (sl2 = ssq - sr2 later)
        acc[s][2] += fabsf(v);                 // sum |v|
        cl[s] += __popcll(__ballot(v < 0.f));
        cr[s] += __popcll(__ballot(v > 0.f));
    };
    // value-only update for the hot loop (counts via scalar masks)
    auto updv = [&](int s, float v) {
        float vp = fmaxf(v, 0.f);
        acc[s][0] = fmaf(vp, vp, acc[s][0]);
        acc[s][1] = fmaf(v, v, acc[s][1]);
        acc[s][2] += fabsf(v);
    };

    // sign-mask state: A = row normP, B = row normP2
    unsigned long long mA = 0, pA = 0, nzA = 0, mB = 0, nzB = 0;
    auto mshl1 = [&](unsigned long long x) -> unsigned long long {
        if constexpr (NSLAB == 1) {
            unsigned long long w = (x >> 3) & 0xFFFFFFFFFFFFULL;   // 48-bit window
            w = ((w << 1) | (w >> 47)) & 0xFFFFFFFFFFFFULL;        // circular
            return w << 3;
        } else return x << 1;
    };
    auto mshr1 = [&](unsigned long long x) -> unsigned long long {
        if constexpr (NSLAB == 1) {
            unsigned long long w = (x >> 3) & 0xFFFFFFFFFFFFULL;
            w = ((w >> 1) | (w << 47)) & 0xFFFFFFFFFFFFULL;
            return w << 3;
        } else return x >> 1;
    };
    auto count_row = [&]() {   // counts for row A (normP) vs row B (normP2)
        cl[0] += __popcll(mA); cr[0] += __popcll(pA);
        { unsigned long long x = mA ^ mshl1(mA), v = nzA & mshl1(nzA);
          int n = __popcll(x & v); cl[1] += n; cr[1] += __popcll(v) - n; }
        { unsigned long long x = mA ^ mB, v = nzA & nzB;
          int n = __popcll(x & v); cl[2] += n; cr[2] += __popcll(v) - n; }
        { unsigned long long x = mA ^ mshl1(mB), v = nzA & mshl1(nzB);
          int n = __popcll(x & v); cl[3] += n; cr[3] += __popcll(v) - n; }
        { unsigned long long x = mA ^ mshr1(mB), v = nzA & mshr1(nzB);
          int n = __popcll(x & v); cl[4] += n; cr[4] += __popcll(v) - n; }
    };

    // prologue: fill 7-row hconv ring (rows r0-3 .. r0+3) + pend row r0+4
    float mr0,mr1,mr2,mr3,mr4,mr5,mr6, qr0,qr1,qr2,qr3,qr4,qr5,qr6;
    float rA, rB, rC, rD;
    float vN = ld();
    { float v=vN; vN=ld(); issue_raw(v); combine_raw(mr0,qr0); }
    { float v=vN; vN=ld(); issue_raw(v); combine_raw(mr1,qr1); }
    { float v=vN; vN=ld(); issue_raw(v); combine_raw(mr2,qr2); }
    { float v=vN; vN=ld(); issue_raw(v); combine_raw(mr3,qr3); rA=v; }
    { float v=vN; vN=ld(); issue_raw(v); combine_raw(mr4,qr4); rB=v; }
    { float v=vN; vN=ld(); issue_raw(v); combine_raw(mr5,qr5); rC=v; }
    { float v=vN; vN=ld(); issue_raw(v); combine_raw(mr6,qr6); rD=v; }
    { float v=vN; vN=ld(); issue_raw(v); }   // pends = row r0+4
    float vN2 = ld();                        // 2-deep prefetch (row r0+6)

    float normP = 0.f, normP2 = 0.f;
    float pendSL = 0.f, pendPL = 0.f, pendPR = 0.f;
    float firstN = 0.f, dsSave = 0.f;
    const bool dsw = WDS && (lane & 1) && (lane >= 3) && (lane <= 49);

    #pragma unroll 4
    for (int yy = 0; yy < SROWS; ++yy) {
        const int y = r0 + yy;
        // 1) stats for row y-1 (pure VALU + SALU counts)
        if (yy > 0) {
            updv(0, normP);
            updv(1, normP * pendSL);
            updv(2, normP * normP2);
            updv(3, normP * pendPL);
            updv(4, normP * pendPR);
            count_row();
        }
        // 2) vertical combine for row y (ring ready since last iter)
        float mu = ((w0*mr0 + w1*mr1) + (w2*mr2 + w3*mr3)) + ((w4*mr4 + w5*mr5) + w6*mr6);
        float s2 = ((w0*qr0 + w1*qr1) + (w2*qr2 + w3*qr3)) + ((w4*qr4 + w5*qr5) + w6*qr6);
        float sig = __builtin_amdgcn_sqrtf(fabsf(s2 - mu * mu));
        float nrm = (rA - mu) * __builtin_amdgcn_rcpf(sig + 1.0f);
        float cur = act ? nrm : 0.f;

        // 3) captures
        if (yy == 0) firstN = cur;
        if constexpr (NSLAB == 2) {
            if (lane == 3)  edgeL[strip][slab][yy] = cur;
            if (lane == 50) edgeR[strip][slab][yy] = cur;
        }
        if (yy == SROWS - 1 && act) lastrow[strip][slab * 48 + lane - 3] = cur;

        // 4) fused 2x2-mean downsample of raw input
        if constexpr (WDS) {
            float hs = rA + __shfl_down(rA, 1);
            if ((y & 1) == 0) dsSave = hs;
            else if (dsw)
                dsout[((size_t)b * (H / 2) + (y >> 1)) * (W / 2) + (gx >> 1)] = 0.25f * (dsSave + hs);
        }

        // 5) product shifts for next iteration's stats; rotate masks
        if constexpr (NSLAB == 2) {
            pendSL = dpp_getL(cur);      // cur[i-1]; lane3 gets cur[2]=0 -> fixup
            pendPL = dpp_getL(normP);    // prev[i-1]
            pendPR = dpp_getR(normP);    // prev[i+1]
        } else {
            pendSL = bperm(am1, cur);
            pendPL = bperm(am1, normP);
            pendPR = bperm(ap1, normP);
        }
        normP2 = normP; normP = cur;
        mB = mA; nzB = nzA;
        mA = __ballot(cur < 0.f);
        pA = __ballot(cur > 0.f);
        nzA = mA | pA;

        // 6) hconv combine for row y+4 (pends issued last iter) + ring shift
        float mh, qh; combine_raw(mh, qh);
        mr0=mr1; mr1=mr2; mr2=mr3; mr3=mr4; mr4=mr5; mr5=mr6; mr6=mh;
        qr0=qr1; qr1=qr2; qr2=qr3; qr3=qr4; qr4=qr5; qr5=qr6; qr6=qh;

        // 7) raw ring shift, issue next raw shifts, rotate 2-deep prefetch
        rA=rB; rB=rC; rC=rD; rD=vHp;
        float vv = vN; vN = vN2; vN2 = ld();
        issue_raw(vv);
    }
    // epilogue: stats for the strip's last row
    updv(0, normP);
    updv(1, normP * pendSL);
    updv(2, normP * normP2);
    updv(3, normP * pendPL);
    updv(4, normP * pendPR);
    count_row();

    __syncthreads();

    // ---- row-seam fixup: products of row r0 with block-circular previous row ----
    {
        const int ps = (strip + NSTRIP - 1) % NSTRIP;
        int j  = slab * 48 + (lane - 3);
        int js = act ? j : 0;
        int jm1 = (js + K - 1) % K;
        int jp1 = (js + 1) % K;
        float pv  = act ? lastrow[ps][js]  : 0.f;
        float pvL = act ? lastrow[ps][jm1] : 0.f;
        float pvR = act ? lastrow[ps][jp1] : 0.f;
        upd(2, firstN * pv);
        upd(3, firstN * pvL);
        upd(4, firstN * pvR);
    }

    // ---- column-seam fixup (K=96 only): slab-edge wrap products ----
    if constexpr (NSLAB == 2) {
        if (lane < SROWS) {
            int r = lane;
            if (slab == 0) {
                float c0  = edgeL[strip][0][r];   // n[r][0]
                float e95 = edgeR[strip][1][r];   // n[r][95]
                upd(1, c0 * e95);
                if (r > 0) {
                    upd(3, c0 * edgeR[strip][1][r - 1]);
                    upd(4, edgeR[strip][0][r] * edgeL[strip][1][r - 1]);  // col47 * n[r-1][48]
                }
            } else {
                float c48 = edgeL[strip][1][r];   // n[r][48]
                float e47 = edgeR[strip][0][r];   // n[r][47]
                upd(1, c48 * e47);
                if (r > 0) {
                    upd(3, c48 * edgeR[strip][0][r - 1]);
                    upd(4, edgeR[strip][1][r] * edgeL[strip][0][r - 1]); // col95 * n[r-1][0]
                }
            }
        }
    }

    // ---- reduce: 15 floats via shuffles; counts are wave-uniform scalars ----
    #pragma unroll
    for (int off = 32; off >= 1; off >>= 1)
        #pragma unroll
        for (int s = 0; s < 5; ++s) {
            acc[s][0] += __shfl_down(acc[s][0], off);
            acc[s][1] += __shfl_down(acc[s][1], off);
            acc[s][2] += __shfl_down(acc[s][2], off);
        }
    if (lane == 0) {
        #pragma unroll
        for (int s = 0; s < 5; ++s) {
            redf[wv][s*3+0] = acc[s][0];
            redf[wv][s*3+1] = acc[s][1];
            redf[wv][s*3+2] = acc[s][2];
            redc[wv][s*2+0] = (float)cl[s];
            redc[wv][s*2+1] = (float)cr[s];
        }
    }
    __syncthreads();
    if (tid < 15) {
        stats[((size_t)b * NBLK + bIdx) * 25 + tid] =
            redf[0][tid] + redf[1][tid] + redf[2][tid] + redf[3][tid];
    } else if (tid < 25) {
        int t = tid - 15;
        stats[((size_t)b * NBLK + bIdx) * 25 + tid] =
            redc[0][t] + redc[1][t] + redc[2][t] + redc[3][t];
    }
}

// ---------------- AGGD closed-form + binary-search argmin ----------------
__global__ __launch_bounds__(256) void aggd_kernel(
        const float* __restrict__ stats1, const float* __restrict__ stats2,
        const float* __restrict__ rgam, const float* __restrict__ convt,
        const float* __restrict__ meanf, float* __restrict__ feats) {
    __shared__ float rg[NGRID];
    for (int i = threadIdx.x; i < NGRID; i += 256) rg[i] = rgam[i];
    __syncthreads();

    int gid = blockIdx.x * 256 + threadIdx.x;
    if (gid >= 2 * BATCH * NBLK * 5) return;
    int s = gid % 5; int t = gid / 5;
    int blk = t % NBLK; t /= NBLK;
    int b = t % BATCH; int scale = t / BATCH;

    const float* st = (scale ? stats2 : stats1) + ((size_t)b * NBLK + blk) * 25;
    float sr2 = st[s*3+0], ssq = st[s*3+1], sab = st[s*3+2];
    float cl = st[15 + 2*s], cr = st[15 + 2*s + 1];
    float sl2 = fmaxf(ssq - sr2, 0.f);
    float n = scale ? (48.f * 48.f) : (96.f * 96.f);

    float lstd = sqrtf(sl2 / (cl + 1e-8f));
    float rstd = sqrtf(sr2 / (cr + 1e-8f));
    float gh = lstd / rstd;
    float mab = sab / n;
    float msq = ssq / n;
    float rhat = mab * mab / msq;
    float g2 = gh * gh;
    float x = rhat * (gh * g2 + 1.f) * (gh + 1.f) / ((g2 + 1.f) * (g2 + 1.f));

    int lo = 0, hi = NGRID;
    while (lo < hi) {
        int mid = (lo + hi) >> 1;
        if (rg[mid] < x) lo = mid + 1; else hi = mid;
    }
    int gi;
    if (lo <= 0) gi = 0;
    else if (lo >= NGRID) gi = NGRID - 1;
    else {
        float dlo = x - rg[lo - 1];
        float dhi = rg[lo] - x;
        gi = (dlo <= dhi) ? lo - 1 : lo;   // tie -> lower index (first-min)
    }

    float alpha = (float)(0.2 + 0.001 * (double)gi);
    float cv = convt[gi];
    float lb = lstd * cv, rb = rstd * cv;
    float* fo = feats + ((size_t)b * NBLK + blk) * NFEAT + (scale ? 18 : 0);
    if (s == 0) {
        fo[0] = alpha;
        fo[1] = 0.5f * (lb + rb);
    } else {
        int o = 2 + (s - 1) * 4;
        fo[o]     = alpha;
        fo[o + 1] = (rb - lb) * meanf[gi];
        fo[o + 2] = lb;
        fo[o + 3] = rb;
    }
}

// ---------------- per-batch covariance + solve + score ----------------
__global__ __launch_bounds__(256) void score_kernel(
        const float* __restrict__ feats, const float* __restrict__ mu_pris,
        const float* __restrict__ cov_pris, float* __restrict__ out) {
    __shared__ float F[NBLK][NFEAT];
    __shared__ double mu[NFEAT];
    __shared__ double A[NFEAT][NFEAT + 1];
    __shared__ double dff[NFEAT];
    __shared__ double xs[NFEAT];
    int b = blockIdx.x, tid = threadIdx.x;
    const float* fp = feats + (size_t)b * NBLK * NFEAT;
    for (int i = tid; i < NBLK * NFEAT; i += 256) F[i / NFEAT][i % NFEAT] = fp[i];
    __syncthreads();
    if (tid < NFEAT) {
        double s = 0.0;
        for (int n = 0; n < NBLK; ++n) s += (double)F[n][tid];
        mu[tid] = s / (double)NBLK;
        dff[tid] = (double)mu_pris[tid] - mu[tid];
    }
    __syncthreads();
    for (int e = tid; e < NFEAT * NFEAT; e += 256) {
        int f = e / NFEAT, g = e % NFEAT;
        double mf = mu[f], mg = mu[g];
        double s = 0.0;
        for (int n = 0; n < NBLK; ++n) s += ((double)F[n][f] - mf) * ((double)F[n][g] - mg);
        A[f][g] = (s / (double)(NBLK - 1) + (double)cov_pris[f * NFEAT + g]) * 0.5;
    }
    if (tid < NFEAT) A[tid][NFEAT] = dff[tid];
    for (int k = 0; k < NFEAT - 1; ++k) {
        __syncthreads();
        double rk = 1.0 / A[k][k];
        for (int e = tid; e < NFEAT * (NFEAT + 1); e += 256) {
            int r = e / (NFEAT + 1), c = e % (NFEAT + 1);
            if (r > k && c > k) A[r][c] -= (A[r][k] * rk) * A[k][c];
        }
    }
    __syncthreads();
    for (int i = NFEAT - 1; i >= 0; --i) {
        if (tid == i) xs[i] = A[i][NFEAT] / A[i][i];
        __syncthreads();
        if (tid < i) A[tid][NFEAT] -= A[tid][i] * xs[i];
    }
    __syncthreads();
    if (tid == 0) {
        double quad = 0.0;
        for (int i = 0; i < NFEAT; ++i) quad += dff[i] * xs[i];
        out[b] = (float)sqrt(fmax(quad, 0.0));
    }
}

// ---------------- launch ----------------
extern "C" void kernel_launch(void* const* d_in, const int* in_sizes, int n_in,
                              void* d_out, int out_size, void* d_ws, size_t ws_size,
                              hipStream_t stream) {
    const float* img      = (const float*)d_in[0];
    const float* mu_pris  = (const float*)d_in[1];
    const float* cov_pris = (const float*)d_in[2];
    float* out = (float*)d_out;
    float* ws = (float*)d_ws;

    float* rgam  = ws;                 // 9801 (pad to 9856)
    float* convt = rgam + 9856;
    float* meanf = convt + 9856;
    float* w1d   = meanf + 9856;       // 8
    float* stats1 = w1d + 8;                           // 16*121*25
    float* stats2 = stats1 + BATCH * NBLK * 25;
    float* feats  = stats2 + BATCH * NBLK * 25;        // 16*121*36
    float* dsimg  = feats + BATCH * NBLK * NFEAT;      // 16*528*528

    init_tables<<<(NGRID + 255) / 256, 256, 0, stream>>>(rgam, convt, meanf, w1d);

    fused_mscn_stats<96, true><<<dim3(NBLK, BATCH), 256, 0, stream>>>(
        img, dsimg, w1d, stats1);
    fused_mscn_stats<48, false><<<dim3(NBLK, BATCH), 256, 0, stream>>>(
        dsimg, nullptr, w1d, stats2);

    aggd_kernel<<<(2 * BATCH * NBLK * 5 + 255) / 256, 256, 0, stream>>>(
        stats1, stats2, rgam, convt, meanf, feats);

    score_kernel<<<BATCH, 256, 0, stream>>>(feats, mu_pris, cov_pris, out);
}

// Round 12
// 157.839 us; speedup vs baseline: 1.6332x; 1.0542x over previous
//
#include <hip/hip_runtime.h>
#include <math.h>

#define NGRID 9801
#define NB 11            // blocks per dim (both scales)
#define NBLK (NB*NB)     // 121
#define BATCH 16
#define NFEAT 36

typedef float v2f __attribute__((ext_vector_type(2)));   // -> v_pk_*_f32

// ---------------- tables ----------------
__global__ void init_tables(float* __restrict__ rgam, float* __restrict__ convt,
                            float* __restrict__ meanf, float* __restrict__ w1d) {
    int i = blockIdx.x * blockDim.x + threadIdx.x;
    if (i < NGRID) {
        double a = (double)(float)(0.2 + 0.001 * (double)i);  // match float32 grid
        double g1 = lgamma(1.0 / a);
        double g2 = lgamma(2.0 / a);
        double g3 = lgamma(3.0 / a);
        rgam[i]  = (float)exp(2.0 * g2 - g1 - g3);
        convt[i] = (float)sqrt(exp(g1 - g3));
        meanf[i] = (float)exp(g2 - g1);
    }
    if (i == 0) {
        double g[7], s = 0.0;
        for (int k = 0; k < 7; ++k) { double d = (double)(k - 3); g[k] = exp(-d * d * 18.0 / 49.0); s += g[k]; }
        for (int k = 0; k < 7; ++k) w1d[k] = (float)(g[k] / s);
    }
}

__device__ __forceinline__ float bperm(int addr, float v) {
    return __int_as_float(__builtin_amdgcn_ds_bpermute(addr, __float_as_int(v)));
}
// DPP wave shifts (VALU pipe, not DS). Validated round 11 (absmax 0).
__device__ __forceinline__ float dpp_getL(float v) {   // lane i <- lane i-1
    return __int_as_float(__builtin_amdgcn_update_dpp(
        0, __float_as_int(v), 0x138 /*WAVE_SHR1*/, 0xF, 0xF, true));
}
__device__ __forceinline__ float dpp_getR(float v) {   // lane i <- lane i+1
    return __int_as_float(__builtin_amdgcn_update_dpp(
        0, __float_as_int(v), 0x130 /*WAVE_SHL1*/, 0xF, 0xF, true));
}

// ---------------- fused MSCN + in-register per-block stats (pipelined) --------
// One WG per (NIQE block, batch). Round-11 structure:
//   K=96: 2 slabs(48 cols) x 2 strips(48 rows) = 4 waves (256 thr).
//   K=48: 1 slab x 4 strips(12 rows) = 4 waves (256 thr).
// Deltas vs round 11: (a) packed-FP32 pairing of the (mu, m2) convolutions and
// (sr2, ssq) accumulators via ext_vector_type(2) -> v_pk_fma_f32; (b) ballot
// counting replaces the 64-bit scalar-mask algebra (SALU relief); (c) global
// prefetch depth 2 -> 4; (d) WDS downsample shuffle -> DPP.
template <int K, bool WDS>
__global__ __launch_bounds__(256) void fused_mscn_stats(
        const float* __restrict__ img, float* __restrict__ dsout,
        const float* __restrict__ w1d, float* __restrict__ stats) {
    constexpr int NSLAB = K / 48;
    constexpr int NSTRIP = 4 / NSLAB;
    constexpr int SROWS = K / NSTRIP;
    constexpr int W = K * NB;
    constexpr int H = W;

    __shared__ float lastrow[NSTRIP][K];            // each strip's last norm row
    __shared__ float edgeL[NSTRIP][NSLAB][SROWS];   // per-row slab-edge norm (K=96)
    __shared__ float edgeR[NSTRIP][NSLAB][SROWS];
    __shared__ float redf[4][15];
    __shared__ float redc[4][10];

    const int tid = threadIdx.x;
    const int lane = tid & 63;
    const int wv = tid >> 6;
    const int slab = wv % NSLAB;
    const int strip = wv / NSLAB;
    const int bIdx = blockIdx.x;
    const int b = blockIdx.y;
    const int bh = bIdx / NB, bw = bIdx % NB;
    const int x0 = bw * K + slab * 48;
    const int gx = x0 - 3 + lane;
    const int gxc = min(max(gx, 0), W - 1);
    const int r0 = bh * K + strip * SROWS;
    const bool act = (lane >= 3) && (lane <= 50);
    int am1 = 0, ap1 = 0;
    if constexpr (NSLAB == 1) {
        am1 = ((lane == 3) ? 50 : (lane - 1)) << 2;   // circular product wrap
        ap1 = ((lane == 50) ? 3 : (lane + 1)) << 2;
    }

    const char* baseB = (const char*)(img + (size_t)b * H * W);
    const float w0=w1d[0], w1=w1d[1], w2=w1d[2], w3=w1d[3], w4=w1d[4], w5=w1d[5], w6=w1d[6];

    // incremental addressing: per-lane byte offset + uniform clamped delta
    int addrB = (min(max(r0 - 3, 0), H - 1) * W + gxc) * 4;
    int rowNext = r0 - 2;                  // uniform: row index of NEXT load
    auto ld = [&]() -> float {
        float v = *(const float*)(baseB + addrB);
        addrB += (rowNext >= 1 && rowNext < H) ? (W * 4) : 0;  // uniform SALU
        ++rowNext;
        return v;
    };

    float pa0, pa1, pa2, pa4, pa5, pa6, vHp;
    auto issue_raw = [&](float v) {
        pa2 = dpp_getL(v);        // lane i-1
        pa1 = dpp_getL(pa2);      // lane i-2
        pa0 = dpp_getL(pa1);      // lane i-3
        pa4 = dpp_getR(v);        // lane i+1
        pa5 = dpp_getR(pa4);      // lane i+2
        pa6 = dpp_getR(pa5);      // lane i+3
        vHp = v;
    };
    auto sq2 = [](float v) -> v2f { v2f t; t.x = v; t.y = v * v; return t; };
    // packed combine: [mu_row, m2_row] via 7x v_pk_fma
    auto combine_raw = [&]() -> v2f {
        v2f r = sq2(pa0) * w0;
        r += sq2(pa1) * w1;
        r += sq2(pa2) * w2;
        r += sq2(vHp) * w3;
        r += sq2(pa4) * w4;
        r += sq2(pa5) * w5;
        r += sq2(pa6) * w6;
        return r;
    };

    v2f accp[5];       // [sr2, ssq] per signal
    float sab[5];
    #pragma unroll
    for (int s = 0; s < 5; ++s) { accp[s] = (v2f)0.f; sab[s] = 0.f; }
    int cl[5] = {0,0,0,0,0}, cr[5] = {0,0,0,0,0};

    auto upd = [&](int s, float v) {
        float vp = fmaxf(v, 0.f);
        v2f t; t.x = vp; t.y = v;
        accp[s] += t * t;                      // pk: sr2 += vp^2, ssq += v^2
        sab[s] += fabsf(v);
        cl[s] += __popcll(__ballot(v < 0.f));
        cr[s] += __popcll(__ballot(v > 0.f));
    };

    // prologue: fill 7-row hconv ring (rows r0-3 .. r0+3) + pend row r0+4
    v2f mq0,mq1,mq2,mq3,mq4,mq5,mq6;
    float rA, rB, rC, rD;
    float vN = ld();
    { float v=vN; vN=ld(); issue_raw(v); mq0=combine_raw(); }
    { float v=vN; vN=ld(); issue_raw(v); mq1=combine_raw(); }
    { float v=vN; vN=ld(); issue_raw(v); mq2=combine_raw(); }
    { float v=vN; vN=ld(); issue_raw(v); mq3=combine_raw(); rA=v; }
    { float v=vN; vN=ld(); issue_raw(v); mq4=combine_raw(); rB=v; }
    { float v=vN; vN=ld(); issue_raw(v); mq5=combine_raw(); rC=v; }
    { float v=vN; vN=ld(); issue_raw(v); mq6=combine_raw(); rD=v; }
    { float v=vN; vN=ld(); issue_raw(v); }   // pends = row r0+4; vN = r0+5
    float vN2 = ld();                        // r0+6
    float vN3 = ld();                        // r0+7
    float vN4 = ld();                        // r0+8  (4-deep prefetch)

    float normP = 0.f, normP2 = 0.f;
    float pendSL = 0.f, pendPL = 0.f, pendPR = 0.f;
    float firstN = 0.f, dsSave = 0.f;
    const bool dsw = WDS && (lane & 1) && (lane >= 3) && (lane <= 49);

    #pragma unroll 4
    for (int yy = 0; yy < SROWS; ++yy) {
        const int y = r0 + yy;
        // 1) stats for row y-1 (pend shifts issued last iter)
        if (yy > 0) {
            upd(0, normP);
            upd(1, normP * pendSL);
            upd(2, normP * normP2);
            upd(3, normP * pendPL);
            upd(4, normP * pendPR);
        }
        // 2) vertical combine for row y (packed [mu, s2])
        v2f ms = mq0 * w0;
        ms += mq1 * w1;
        ms += mq2 * w2;
        ms += mq3 * w3;
        ms += mq4 * w4;
        ms += mq5 * w5;
        ms += mq6 * w6;
        float mu = ms.x, s2 = ms.y;
        float sig = __builtin_amdgcn_sqrtf(fabsf(s2 - mu * mu));
        float nrm = (rA - mu) * __builtin_amdgcn_rcpf(sig + 1.0f);
        float cur = act ? nrm : 0.f;

        // 3) captures
        if (yy == 0) firstN = cur;
        if constexpr (NSLAB == 2) {
            if (lane == 3)  edgeL[strip][slab][yy] = cur;
            if (lane == 50) edgeR[strip][slab][yy] = cur;
        }
        if (yy == SROWS - 1 && act) lastrow[strip][slab * 48 + lane - 3] = cur;

        // 4) fused 2x2-mean downsample of raw input (DPP, not DS)
        if constexpr (WDS) {
            float hs = rA + dpp_getR(rA);
            if ((y & 1) == 0) dsSave = hs;
            else if (dsw)
                dsout[((size_t)b * (H / 2) + (y >> 1)) * (W / 2) + (gx >> 1)] = 0.25f * (dsSave + hs);
        }

        // 5) product shifts for next iteration's stats
        if constexpr (NSLAB == 2) {
            pendSL = dpp_getL(cur);      // cur[i-1]; lane3 gets 0 -> fixup
            pendPL = dpp_getL(normP);    // prev[i-1]
            pendPR = dpp_getR(normP);    // prev[i+1]
        } else {
            pendSL = bperm(am1, cur);
            pendPL = bperm(am1, normP);
            pendPR = bperm(ap1, normP);
        }
        normP2 = normP; normP = cur;

        // 6) hconv combine for row y+4 (pends issued last iter) + ring shift
        v2f mh = combine_raw();
        mq0=mq1; mq1=mq2; mq2=mq3; mq3=mq4; mq4=mq5; mq5=mq6; mq6=mh;

        // 7) raw ring shift, issue next raw shifts, rotate 4-deep prefetch
        rA=rB; rB=rC; rC=rD; rD=vHp;
        float vv = vN; vN=vN2; vN2=vN3; vN3=vN4; vN4=ld();
        issue_raw(vv);
    }
    // epilogue: stats for the strip's last row
    upd(0, normP);
    upd(1, normP * pendSL);
    upd(2, normP * normP2);
    upd(3, normP * pendPL);
    upd(4, normP * pendPR);

    __syncthreads();

    // ---- row-seam fixup: products of row r0 with block-circular previous row ----
    {
        const int ps = (strip + NSTRIP - 1) % NSTRIP;
        int j  = slab * 48 + (lane - 3);
        int js = act ? j : 0;
        int jm1 = (js + K - 1) % K;
        int jp1 = (js + 1) % K;
        float pv  = act ? lastrow[ps][js]  : 0.f;
        float pvL = act ? lastrow[ps][jm1] : 0.f;
        float pvR = act ? lastrow[ps][jp1] : 0.f;
        upd(2, firstN * pv);
        upd(3, firstN * pvL);
        upd(4, firstN * pvR);
    }

    // ---- column-seam fixup (K=96 only): slab-edge wrap products ----
    if constexpr (NSLAB == 2) {
        if (lane < SROWS) {
            int r = lane;
            if (slab == 0) {
                float c0  = edgeL[strip][0][r];   // n[r][0]
                float e95 = edgeR[strip][1][r];   // n[r][95]
                upd(1, c0 * e95);
                if (r > 0) {
                    upd(3, c0 * edgeR[strip][1][r - 1]);
                    upd(4, edgeR[strip][0][r] * edgeL[strip][1][r - 1]);  // col47 * n[r-1][48]
                }
            } else {
                float c48 = edgeL[strip][1][r];   // n[r][48]
                float e47 = edgeR[strip][0][r];   // n[r][47]
                upd(1, c48 * e47);
                if (r > 0) {
                    upd(3, c48 * edgeR[strip][0][r - 1]);
                    upd(4, edgeR[strip][1][r] * edgeL[strip][0][r - 1]); // col95 * n[r-1][0]
                }
            }
        }
    }

    // ---- reduce: 15 floats via shuffles; counts via LDS ----
    #pragma unroll
    for (int off = 32; off >= 1; off >>= 1)
        #pragma unroll
        for (int s = 0; s < 5; ++s) {
            accp[s].x += __shfl_down(accp[s].x, off);
            accp[s].y += __shfl_down(accp[s].y, off);
            sab[s]    += __shfl_down(sab[s],    off);
        }
    if (lane == 0) {
        #pragma unroll
        for (int s = 0; s < 5; ++s) {
            redf[wv][s*3+0] = accp[s].x;
            redf[wv][s*3+1] = accp[s].y;
            redf[wv][s*3+2] = sab[s];
            redc[wv][s*2+0] = (float)cl[s];
            redc[wv][s*2+1] = (float)cr[s];
        }
    }
    __syncthreads();
    if (tid < 15) {
        stats[((size_t)b * NBLK + bIdx) * 25 + tid] =
            redf[0][tid] + redf[1][tid] + redf[2][tid] + redf[3][tid];
    } else if (tid < 25) {
        int t = tid - 15;
        stats[((size_t)b * NBLK + bIdx) * 25 + tid] =
            redc[0][t] + redc[1][t] + redc[2][t] + redc[3][t];
    }
}

// ---------------- AGGD closed-form + binary-search argmin ----------------
__global__ __launch_bounds__(256) void aggd_kernel(
        const float* __restrict__ stats1, const float* __restrict__ stats2,
        const float* __restrict__ rgam, const float* __restrict__ convt,
        const float* __restrict__ meanf, float* __restrict__ feats) {
    __shared__ float rg[NGRID];
    for (int i = threadIdx.x; i < NGRID; i += 256) rg[i] = rgam[i];
    __syncthreads();

    int gid = blockIdx.x * 256 + threadIdx.x;
    if (gid >= 2 * BATCH * NBLK * 5) return;
    int s = gid % 5; int t = gid / 5;
    int blk = t % NBLK; t /= NBLK;
    int b = t % BATCH; int scale = t / BATCH;

    const float* st = (scale ? stats2 : stats1) + ((size_t)b * NBLK + blk) * 25;
    float sr2 = st[s*3+0], ssq = st[s*3+1], sab = st[s*3+2];
    float cl = st[15 + 2*s], cr = st[15 + 2*s + 1];
    float sl2 = fmaxf(ssq - sr2, 0.f);
    float n = scale ? (48.f * 48.f) : (96.f * 96.f);

    float lstd = sqrtf(sl2 / (cl + 1e-8f));
    float rstd = sqrtf(sr2 / (cr + 1e-8f));
    float gh = lstd / rstd;
    float mab = sab / n;
    float msq = ssq / n;
    float rhat = mab * mab / msq;
    float g2 = gh * gh;
    float x = rhat * (gh * g2 + 1.f) * (gh + 1.f) / ((g2 + 1.f) * (g2 + 1.f));

    int lo = 0, hi = NGRID;
    while (lo < hi) {
        int mid = (lo + hi) >> 1;
        if (rg[mid] < x) lo = mid + 1; else hi = mid;
    }
    int gi;
    if (lo <= 0) gi = 0;
    else if (lo >= NGRID) gi = NGRID - 1;
    else {
        float dlo = x - rg[lo - 1];
        float dhi = rg[lo] - x;
        gi = (dlo <= dhi) ? lo - 1 : lo;   // tie -> lower index (first-min)
    }

    float alpha = (float)(0.2 + 0.001 * (double)gi);
    float cv = convt[gi];
    float lb = lstd * cv, rb = rstd * cv;
    float* fo = feats + ((size_t)b * NBLK + blk) * NFEAT + (scale ? 18 : 0);
    if (s == 0) {
        fo[0] = alpha;
        fo[1] = 0.5f * (lb + rb);
    } else {
        int o = 2 + (s - 1) * 4;
        fo[o]     = alpha;
        fo[o + 1] = (rb - lb) * meanf[gi];
        fo[o + 2] = lb;
        fo[o + 3] = rb;
    }
}

// ---------------- per-batch covariance + solve + score ----------------
__global__ __launch_bounds__(256) void score_kernel(
        const float* __restrict__ feats, const float* __restrict__ mu_pris,
        const float* __restrict__ cov_pris, float* __restrict__ out) {
    __shared__ float F[NBLK][NFEAT];
    __shared__ double mu[NFEAT];
    __shared__ double A[NFEAT][NFEAT + 1];
    __shared__ double dff[NFEAT];
    __shared__ double xs[NFEAT];
    int b = blockIdx.x, tid = threadIdx.x;
    const float* fp = feats + (size_t)b * NBLK * NFEAT;
    for (int i = tid; i < NBLK * NFEAT; i += 256) F[i / NFEAT][i % NFEAT] = fp[i];
    __syncthreads();
    if (tid < NFEAT) {
        double s = 0.0;
        for (int n = 0; n < NBLK; ++n) s += (double)F[n][tid];
        mu[tid] = s / (double)NBLK;
        dff[tid] = (double)mu_pris[tid] - mu[tid];
    }
    __syncthreads();
    for (int e = tid; e < NFEAT * NFEAT; e += 256) {
        int f = e / NFEAT, g = e % NFEAT;
        double mf = mu[f], mg = mu[g];
        double s = 0.0;
        for (int n = 0; n < NBLK; ++n) s += ((double)F[n][f] - mf) * ((double)F[n][g] - mg);
        A[f][g] = (s / (double)(NBLK - 1) + (double)cov_pris[f * NFEAT + g]) * 0.5;
    }
    if (tid < NFEAT) A[tid][NFEAT] = dff[tid];
    for (int k = 0; k < NFEAT - 1; ++k) {
        __syncthreads();
        double rk = 1.0 / A[k][k];
        for (int e = tid; e < NFEAT * (NFEAT + 1); e += 256) {
            int r = e / (NFEAT + 1), c = e % (NFEAT + 1);
            if (r > k && c > k) A[r][c] -= (A[r][k] * rk) * A[k][c];
        }
    }
    __syncthreads();
    for (int i = NFEAT - 1; i >= 0; --i) {
        if (tid == i) xs[i] = A[i][NFEAT] / A[i][i];
        __syncthreads();
        if (tid < i) A[tid][NFEAT] -= A[tid][i] * xs[i];
    }
    __syncthreads();
    if (tid == 0) {
        double quad = 0.0;
        for (int i = 0; i < NFEAT; ++i) quad += dff[i] * xs[i];
        out[b] = (float)sqrt(fmax(quad, 0.0));
    }
}

// ---------------- launch ----------------
extern "C" void kernel_launch(void* const* d_in, const int* in_sizes, int n_in,
                              void* d_out, int out_size, void* d_ws, size_t ws_size,
                              hipStream_t stream) {
    const float* img      = (const float*)d_in[0];
    const float* mu_pris  = (const float*)d_in[1];
    const float* cov_pris = (const float*)d_in[2];
    float* out = (float*)d_out;
    float* ws = (float*)d_ws;

    float* rgam  = ws;                 // 9801 (pad to 9856)
    float* convt = rgam + 9856;
    float* meanf = convt + 9856;
    float* w1d   = meanf + 9856;       // 8
    float* stats1 = w1d + 8;                           // 16*121*25
    float* stats2 = stats1 + BATCH * NBLK * 25;
    float* feats  = stats2 + BATCH * NBLK * 25;        // 16*121*36
    float* dsimg  = feats + BATCH * NBLK * NFEAT;      // 16*528*528

    init_tables<<<(NGRID + 255) / 256, 256, 0, stream>>>(rgam, convt, meanf, w1d);

    fused_mscn_stats<96, true><<<dim3(NBLK, BATCH), 256, 0, stream>>>(
        img, dsimg, w1d, stats1);
    fused_mscn_stats<48, false><<<dim3(NBLK, BATCH), 256, 0, stream>>>(
        dsimg, nullptr, w1d, stats2);

    aggd_kernel<<<(2 * BATCH * NBLK * 5 + 255) / 256, 256, 0, stream>>>(
        stats1, stats2, rgam, convt, meanf, feats);

    score_kernel<<<BATCH, 256, 0, stream>>>(feats, mu_pris, cov_pris, out);
}